// Round 3
// baseline (1756.673 us; speedup 1.0000x reference)
//
#include <hip/hip_runtime.h>

#define N_NODES 100000
#define N_EDGES 1600000
#define HD 128
#define NLAYERS 4
#define COUT 40
#define BN_EPS 1e-5f
constexpr int NB = (N_NODES + 255) / 256;   // 391 scan blocks
constexpr int GB = (N_NODES + 127) / 128;   // 782 gemm blocks

typedef _Float16 half8 __attribute__((ext_vector_type(8)));
typedef float floatx4 __attribute__((ext_vector_type(4)));

// ---- weight transpose + fp32->fp16 prep: Wt[n][k] so B-fragments are contiguous ----
__global__ void prep_kernel(const float* __restrict__ W_in,
                            const float* __restrict__ Wl,
                            const float* __restrict__ Wr,
                            const float* __restrict__ W_out,
                            _Float16* __restrict__ Wt_in,    // [128][128]
                            _Float16* __restrict__ Wt_cat,   // [4][128][256] (k<128->Wl, k>=128->Wr)
                            _Float16* __restrict__ Wt_out)   // [48][128], rows(n) >= 40 zero
{
    int tid = blockIdx.x * blockDim.x + threadIdx.x;
    int stride = gridDim.x * blockDim.x;
    for (int idx = tid; idx < 128 * 128; idx += stride) {
        int n = idx >> 7, k = idx & 127;
        Wt_in[idx] = (_Float16)W_in[k * 128 + n];
    }
    for (int idx = tid; idx < 4 * 128 * 256; idx += stride) {
        int i = idx >> 15;
        int r = idx & 32767;
        int n = r >> 8, k = r & 255;
        Wt_cat[idx] = (_Float16)((k < 128) ? Wl[i * 16384 + k * 128 + n]
                                           : Wr[i * 16384 + (k - 128) * 128 + n]);
    }
    for (int idx = tid; idx < 48 * 128; idx += stride) {
        int n = idx >> 7, k = idx & 127;
        Wt_out[idx] = (n < COUT) ? (_Float16)W_out[k * COUT + n] : (_Float16)0.f;
    }
}

// ---- CSR build ----
__global__ void hist_kernel(const int* __restrict__ dst, int* __restrict__ deg) {
    int tid = blockIdx.x * blockDim.x + threadIdx.x;
    int stride = gridDim.x * blockDim.x;
    for (int e = tid; e < N_EDGES; e += stride)
        atomicAdd(&deg[dst[e]], 1);
}

__global__ __launch_bounds__(256) void scan1_kernel(const int* __restrict__ deg, int* __restrict__ bsum) {
    __shared__ int s[256];
    int i = blockIdx.x * 256 + threadIdx.x;
    s[threadIdx.x] = (i < N_NODES) ? deg[i] : 0;
    __syncthreads();
    for (int off = 128; off > 0; off >>= 1) {
        if (threadIdx.x < off) s[threadIdx.x] += s[threadIdx.x + off];
        __syncthreads();
    }
    if (threadIdx.x == 0) bsum[blockIdx.x] = s[0];
}

__global__ void scan2_kernel(int* __restrict__ bsum, int* __restrict__ rs) {
    // one wave: exclusive scan of NB block sums
    int lane = threadIdx.x;
    int run = 0;
    for (int base = 0; base < NB; base += 64) {
        int i = base + lane;
        int orig = (i < NB) ? bsum[i] : 0;
        int v = orig;
        #pragma unroll
        for (int off = 1; off < 64; off <<= 1) {
            int t = __shfl_up(v, off);
            if (lane >= off) v += t;
        }
        int total = __shfl(v, 63);
        if (i < NB) bsum[i] = v - orig + run;
        run += total;
    }
    if (lane == 0) rs[N_NODES] = run;  // == N_EDGES
}

__global__ __launch_bounds__(256) void scan3_kernel(int* __restrict__ rs, int* __restrict__ cur,
                                                    const int* __restrict__ bsum) {
    __shared__ int s[256];
    int i = blockIdx.x * 256 + threadIdx.x;
    int v = (i < N_NODES) ? rs[i] : 0;
    s[threadIdx.x] = v;
    __syncthreads();
    for (int off = 1; off < 256; off <<= 1) {
        int t = 0;
        if ((int)threadIdx.x >= off) t = s[threadIdx.x - off];
        __syncthreads();
        s[threadIdx.x] += t;
        __syncthreads();
    }
    if (i < N_NODES) {
        int excl = s[threadIdx.x] - v + bsum[blockIdx.x];
        rs[i] = excl;
        cur[i] = excl;
    }
}

__global__ void scatter_kernel(const int* __restrict__ src, const int* __restrict__ dst,
                               int* __restrict__ cur, int* __restrict__ ssrc) {
    int tid = blockIdx.x * blockDim.x + threadIdx.x;
    int stride = gridDim.x * blockDim.x;
    for (int e = tid; e < N_EDGES; e += stride) {
        int p = atomicAdd(&cur[dst[e]], 1);
        ssrc[p] = src[e];
    }
}

// ---- mean aggregation: one wave per dst node, 4 groups x 16 lanes, 16B loads ----
// Group g covers a contiguous quarter of the node's edge list; lane covers cols
// [l16*8, l16*8+8). Cross-group reduce via shfl_xor(16/32) at the end.
__global__ __launch_bounds__(256) void aggregate_kernel(const _Float16* __restrict__ H,
                                                        const int* __restrict__ rs,
                                                        const int* __restrict__ ssrc,
                                                        _Float16* __restrict__ AGG) {
    int wid = (blockIdx.x * 256 + threadIdx.x) >> 6;
    int lane = threadIdx.x & 63;
    int grp = lane >> 4, l16 = lane & 15;
    int e0 = rs[wid], e1 = rs[wid + 1];
    int deg = e1 - e0;
    int q = (deg + 3) >> 2;
    int e = e0 + grp * q;
    int ge = min(e + q, e1);

    float acc[8] = {0.f, 0.f, 0.f, 0.f, 0.f, 0.f, 0.f, 0.f};
    const _Float16* __restrict__ Hc = H + l16 * 8;

    for (; e + 4 <= ge; e += 4) {
        int s0 = ssrc[e], s1 = ssrc[e + 1], s2 = ssrc[e + 2], s3 = ssrc[e + 3];
        half8 v0 = *(const half8*)(Hc + (long)s0 * HD);
        half8 v1 = *(const half8*)(Hc + (long)s1 * HD);
        half8 v2 = *(const half8*)(Hc + (long)s2 * HD);
        half8 v3 = *(const half8*)(Hc + (long)s3 * HD);
        #pragma unroll
        for (int j = 0; j < 8; ++j)
            acc[j] += ((float)v0[j] + (float)v1[j]) + ((float)v2[j] + (float)v3[j]);
    }
    for (; e < ge; ++e) {
        int s0 = ssrc[e];
        half8 v0 = *(const half8*)(Hc + (long)s0 * HD);
        #pragma unroll
        for (int j = 0; j < 8; ++j) acc[j] += (float)v0[j];
    }

    #pragma unroll
    for (int j = 0; j < 8; ++j) {
        acc[j] += __shfl_xor(acc[j], 16);
        acc[j] += __shfl_xor(acc[j], 32);
    }
    if (grp == 0) {
        float inv = 1.f / (float)max(deg, 1);
        half8 o;
        #pragma unroll
        for (int j = 0; j < 8; ++j) o[j] = (_Float16)(acc[j] * inv);
        *(half8*)(AGG + (long)wid * HD + l16 * 8) = o;
    }
}

// ---- MFMA GEMM: Y[r][c] = concat(A0,A1)[r][:] . Wt[c][:] + bias[c] ----
// A-fragment: lane holds A[row0 + (lane&15)][quad*8 + j]  (16B contiguous)
// B-fragment: lane holds Wt[c*16 + (lane&15)][quad*8 + j] (16B contiguous)
// C-fragment: lane holds C[row0 + quad*4 + i][c*16 + (lane&15)]
// STATS: also emit per-block column sums / sq-sums of the stored output.
template <int CT, int KS, bool HAS_A1, bool A_F32, bool OUT_F32, bool STATS>
__global__ __launch_bounds__(256) void gemm_kernel(const void* __restrict__ A0v,
                                                   const _Float16* __restrict__ A1,
                                                   const _Float16* __restrict__ Wt,
                                                   const float* __restrict__ bias,
                                                   void* __restrict__ Yv,
                                                   int out_stride, int ncols,
                                                   float* __restrict__ psum,
                                                   float* __restrict__ psq) {
    constexpr int K = KS * 32;
    int wave = threadIdx.x >> 6;
    int lane = threadIdx.x & 63;
    int quad = lane >> 4;
    int l16 = lane & 15;
    int row_base = (blockIdx.x * 4 + wave) * 32;
    bool active = row_base < N_NODES;

    __shared__ float lsum[128], lsq[128];
    if (STATS) {
        if (threadIdx.x < 128) { lsum[threadIdx.x] = 0.f; lsq[threadIdx.x] = 0.f; }
        __syncthreads();
    } else {
        if (!active) return;
    }

    floatx4 acc[2][CT];
    #pragma unroll
    for (int rt = 0; rt < 2; ++rt)
        #pragma unroll
        for (int c = 0; c < CT; ++c)
            acc[rt][c] = (floatx4){0.f, 0.f, 0.f, 0.f};

    if (active) {
        #pragma unroll
        for (int s = 0; s < KS; ++s) {
            int kk = s * 32 + quad * 8;
            half8 afrag[2];
            #pragma unroll
            for (int rt = 0; rt < 2; ++rt) {
                int r = row_base + rt * 16 + l16;
                if (r > N_NODES - 1) r = N_NODES - 1;  // clamp read, store guarded below
                if (A_F32) {
                    const float* p = (const float*)A0v + (long)r * 128 + kk;
                    floatx4 f0 = *(const floatx4*)p;
                    floatx4 f1 = *(const floatx4*)(p + 4);
                    #pragma unroll
                    for (int j = 0; j < 4; ++j) {
                        afrag[rt][j]     = (_Float16)f0[j];
                        afrag[rt][4 + j] = (_Float16)f1[j];
                    }
                } else {
                    const _Float16* p;
                    if (HAS_A1 && kk >= 128) p = A1 + (long)r * 128 + (kk - 128);
                    else                     p = (const _Float16*)A0v + (long)r * 128 + kk;
                    afrag[rt] = *(const half8*)p;
                }
            }
            #pragma unroll
            for (int c = 0; c < CT; ++c) {
                half8 bfrag = *(const half8*)(Wt + (c * 16 + l16) * K + kk);
                #pragma unroll
                for (int rt = 0; rt < 2; ++rt)
                    acc[rt][c] = __builtin_amdgcn_mfma_f32_16x16x32_f16(afrag[rt], bfrag, acc[rt][c], 0, 0, 0);
            }
        }
    }

    #pragma unroll
    for (int c = 0; c < CT; ++c) {
        int col = c * 16 + l16;
        float s_c = 0.f, q_c = 0.f;
        if (active && col < ncols) {
            float bv = bias[col];
            #pragma unroll
            for (int rt = 0; rt < 2; ++rt) {
                #pragma unroll
                for (int i = 0; i < 4; ++i) {
                    int r = row_base + rt * 16 + quad * 4 + i;
                    if (r < N_NODES) {
                        float v = acc[rt][c][i] + bv;
                        if (OUT_F32) ((float*)Yv)[(long)r * out_stride + col] = v;
                        else         ((_Float16*)Yv)[(long)r * out_stride + col] = (_Float16)v;
                        if (STATS) { s_c += v; q_c += v * v; }
                    }
                }
            }
        }
        if (STATS) {
            s_c += __shfl_xor(s_c, 16); s_c += __shfl_xor(s_c, 32);
            q_c += __shfl_xor(q_c, 16); q_c += __shfl_xor(q_c, 32);
            if (lane < 16 && active) {
                atomicAdd(&lsum[col], s_c);
                atomicAdd(&lsq[col], q_c);
            }
        }
    }

    if (STATS) {
        __syncthreads();
        if (threadIdx.x < 128) {
            psum[blockIdx.x * 128 + threadIdx.x] = lsum[threadIdx.x];
            psq [blockIdx.x * 128 + threadIdx.x] = lsq[threadIdx.x];
        }
    }
}

__global__ void bn_reduce_kernel(const float* __restrict__ psum, const float* __restrict__ psq,
                                 const float* __restrict__ g, const float* __restrict__ b,
                                 float* __restrict__ ss, int nb) {
    int col = threadIdx.x;  // 128 threads
    float s = 0.f, q = 0.f;
    for (int i = 0; i < nb; ++i) { s += psum[i * 128 + col]; q += psq[i * 128 + col]; }
    float m = s / (float)N_NODES;
    float v = q / (float)N_NODES - m * m;
    float sc = g[col] * rsqrtf(v + BN_EPS);
    ss[col] = sc;
    ss[128 + col] = b[col] - m * sc;
}

__global__ __launch_bounds__(256) void bn_apply_kernel(const _Float16* __restrict__ Y,
                                                       const float* __restrict__ ss,
                                                       _Float16* __restrict__ H) {
    long total = (long)N_NODES * HD / 8;
    for (long t = (long)blockIdx.x * blockDim.x + threadIdx.x; t < total;
         t += (long)gridDim.x * blockDim.x) {
        long base = t * 8;
        int col0 = (int)(base & 127);
        half8 in = *(const half8*)(Y + base);
        half8 outv;
        #pragma unroll
        for (int j = 0; j < 8; ++j) {
            float v = (float)in[j];
            float r = v * ss[col0 + j] + ss[128 + col0 + j];
            outv[j] = (_Float16)fmaxf(r, 0.f);
        }
        *(half8*)(H + base) = outv;
    }
}

extern "C" void kernel_launch(void* const* d_in, const int* in_sizes, int n_in,
                              void* d_out, int out_size, void* d_ws, size_t ws_size,
                              hipStream_t stream) {
    (void)in_sizes; (void)n_in; (void)out_size; (void)ws_size;
    const float* x       = (const float*)d_in[0];
    const float* W_in    = (const float*)d_in[1];
    const float* b_in    = (const float*)d_in[2];
    const float* g_in    = (const float*)d_in[3];
    const float* beta_in = (const float*)d_in[4];
    const float* Wl      = (const float*)d_in[5];
    const float* bl      = (const float*)d_in[6];
    const float* Wr      = (const float*)d_in[7];
    const float* g_bn    = (const float*)d_in[8];
    const float* b_bn    = (const float*)d_in[9];
    const float* W_out   = (const float*)d_in[10];
    const float* b_out   = (const float*)d_in[11];
    const int*   ei      = (const int*)d_in[12];
    const int* esrc = ei;
    const int* edst = ei + N_EDGES;
    float* out = (float*)d_out;

    char* w = (char*)d_ws;
    auto alloc = [&](size_t bytes) -> char* {
        char* p = w; w += (bytes + 255) & ~(size_t)255; return p;
    };
    int* rs           = (int*)alloc((N_NODES + 1) * sizeof(int));  // deg -> row_start
    int* cur          = (int*)alloc(N_NODES * sizeof(int));
    int* bsum         = (int*)alloc(512 * sizeof(int));
    int* ssrc         = (int*)alloc(N_EDGES * sizeof(int));
    _Float16* Wt_in   = (_Float16*)alloc(128 * 128 * 2);
    _Float16* Wt_cat  = (_Float16*)alloc(4 * 128 * 256 * 2);
    _Float16* Wt_out  = (_Float16*)alloc(48 * 128 * 2);
    _Float16* hbuf    = (_Float16*)alloc((size_t)N_NODES * HD * 2);
    _Float16* agg     = (_Float16*)alloc((size_t)N_NODES * HD * 2);
    _Float16* ybuf    = (_Float16*)alloc((size_t)N_NODES * HD * 2);
    float* psum       = (float*)alloc((size_t)GB * 128 * 4);
    float* psq        = (float*)alloc((size_t)GB * 128 * 4);
    float* ss         = (float*)alloc(256 * 4);

    hipMemsetAsync(rs, 0, (N_NODES + 1) * sizeof(int), stream);
    prep_kernel<<<256, 256, 0, stream>>>(W_in, Wl, Wr, W_out, Wt_in, Wt_cat, Wt_out);
    hist_kernel<<<2048, 256, 0, stream>>>(edst, rs);
    scan1_kernel<<<NB, 256, 0, stream>>>(rs, bsum);
    scan2_kernel<<<1, 64, 0, stream>>>(bsum, rs);
    scan3_kernel<<<NB, 256, 0, stream>>>(rs, cur, bsum);
    scatter_kernel<<<2048, 256, 0, stream>>>(esrc, edst, cur, ssrc);

    // input layer: y = x @ W_in + b_in ; h = relu(bn(y))  (stats fused in gemm)
    gemm_kernel<8, 4, false, true, false, true><<<GB, 256, 0, stream>>>(
        x, nullptr, Wt_in, b_in, ybuf, HD, HD, psum, psq);
    bn_reduce_kernel<<<1, 128, 0, stream>>>(psum, psq, g_in, beta_in, ss, GB);
    bn_apply_kernel<<<1600, 256, 0, stream>>>(ybuf, ss, hbuf);

    for (int i = 0; i < NLAYERS; ++i) {
        aggregate_kernel<<<N_NODES / 4, 256, 0, stream>>>(hbuf, rs, ssrc, agg);
        if (i < NLAYERS - 1) {
            gemm_kernel<8, 8, true, false, false, true><<<GB, 256, 0, stream>>>(
                agg, hbuf, Wt_cat + i * 128 * 256, bl + i * 128, ybuf, HD, HD, psum, psq);
            bn_reduce_kernel<<<1, 128, 0, stream>>>(psum, psq, g_bn + i * 128, b_bn + i * 128, ss, GB);
            bn_apply_kernel<<<1600, 256, 0, stream>>>(ybuf, ss, hbuf);
        } else {
            gemm_kernel<8, 8, true, false, false, false><<<GB, 256, 0, stream>>>(
                agg, hbuf, Wt_cat + i * 128 * 256, bl + i * 128, ybuf, HD, HD, psum, psq);
        }
    }

    // output layer: out = h4 @ W_out + b_out  (h4 lives in ybuf, no BN on last layer)
    gemm_kernel<3, 4, false, false, true, false><<<GB, 256, 0, stream>>>(
        ybuf, nullptr, Wt_out, b_out, out, COUT, COUT, psum, psq);
}

// Round 4
// 942.558 us; speedup vs baseline: 1.8637x; 1.8637x over previous
//
#include <hip/hip_runtime.h>

#define N_NODES 100000
#define N_EDGES 1600000
#define HD 128
#define NLAYERS 4
#define COUT 40
#define BN_EPS 1e-5f
constexpr int NB = (N_NODES + 255) / 256;   // 391 scan blocks
constexpr int GB = (N_NODES + 127) / 128;   // 782 gemm blocks

typedef _Float16 half8 __attribute__((ext_vector_type(8)));
typedef float floatx4 __attribute__((ext_vector_type(4)));

// ---- weight transpose + fp32->fp16 prep: Wt[n][k] so B-fragments are contiguous ----
__global__ void prep_kernel(const float* __restrict__ W_in,
                            const float* __restrict__ Wl,
                            const float* __restrict__ Wr,
                            const float* __restrict__ W_out,
                            _Float16* __restrict__ Wt_in,    // [128][128]
                            _Float16* __restrict__ Wt_cat,   // [4][128][256] (k<128->Wl, k>=128->Wr)
                            _Float16* __restrict__ Wt_out)   // [48][128], rows(n) >= 40 zero
{
    int tid = blockIdx.x * blockDim.x + threadIdx.x;
    int stride = gridDim.x * blockDim.x;
    for (int idx = tid; idx < 128 * 128; idx += stride) {
        int n = idx >> 7, k = idx & 127;
        Wt_in[idx] = (_Float16)W_in[k * 128 + n];
    }
    for (int idx = tid; idx < 4 * 128 * 256; idx += stride) {
        int i = idx >> 15;
        int r = idx & 32767;
        int n = r >> 8, k = r & 255;
        Wt_cat[idx] = (_Float16)((k < 128) ? Wl[i * 16384 + k * 128 + n]
                                           : Wr[i * 16384 + (k - 128) * 128 + n]);
    }
    for (int idx = tid; idx < 48 * 128; idx += stride) {
        int n = idx >> 7, k = idx & 127;
        Wt_out[idx] = (n < COUT) ? (_Float16)W_out[k * COUT + n] : (_Float16)0.f;
    }
}

// ---- CSR build ----
__global__ void hist_kernel(const int* __restrict__ dst, int* __restrict__ deg) {
    int tid = blockIdx.x * blockDim.x + threadIdx.x;
    int stride = gridDim.x * blockDim.x;
    for (int e = tid; e < N_EDGES; e += stride)
        atomicAdd(&deg[dst[e]], 1);
}

__global__ __launch_bounds__(256) void scan1_kernel(const int* __restrict__ deg, int* __restrict__ bsum) {
    __shared__ int s[256];
    int i = blockIdx.x * 256 + threadIdx.x;
    s[threadIdx.x] = (i < N_NODES) ? deg[i] : 0;
    __syncthreads();
    for (int off = 128; off > 0; off >>= 1) {
        if (threadIdx.x < off) s[threadIdx.x] += s[threadIdx.x + off];
        __syncthreads();
    }
    if (threadIdx.x == 0) bsum[blockIdx.x] = s[0];
}

__global__ void scan2_kernel(int* __restrict__ bsum, int* __restrict__ rs) {
    // one wave: exclusive scan of NB block sums
    int lane = threadIdx.x;
    int run = 0;
    for (int base = 0; base < NB; base += 64) {
        int i = base + lane;
        int orig = (i < NB) ? bsum[i] : 0;
        int v = orig;
        #pragma unroll
        for (int off = 1; off < 64; off <<= 1) {
            int t = __shfl_up(v, off);
            if (lane >= off) v += t;
        }
        int total = __shfl(v, 63);
        if (i < NB) bsum[i] = v - orig + run;
        run += total;
    }
    if (lane == 0) rs[N_NODES] = run;  // == N_EDGES
}

__global__ __launch_bounds__(256) void scan3_kernel(int* __restrict__ rs, int* __restrict__ cur,
                                                    const int* __restrict__ bsum) {
    __shared__ int s[256];
    int i = blockIdx.x * 256 + threadIdx.x;
    int v = (i < N_NODES) ? rs[i] : 0;
    s[threadIdx.x] = v;
    __syncthreads();
    for (int off = 1; off < 256; off <<= 1) {
        int t = 0;
        if ((int)threadIdx.x >= off) t = s[threadIdx.x - off];
        __syncthreads();
        s[threadIdx.x] += t;
        __syncthreads();
    }
    if (i < N_NODES) {
        int excl = s[threadIdx.x] - v + bsum[blockIdx.x];
        rs[i] = excl;
        cur[i] = excl;
    }
}

__global__ void scatter_kernel(const int* __restrict__ src, const int* __restrict__ dst,
                               int* __restrict__ cur, int* __restrict__ ssrc) {
    int tid = blockIdx.x * blockDim.x + threadIdx.x;
    int stride = gridDim.x * blockDim.x;
    for (int e = tid; e < N_EDGES; e += stride) {
        int p = atomicAdd(&cur[dst[e]], 1);
        ssrc[p] = src[e];
    }
}

// ---- mean aggregation: one wave per dst node, 4 groups x 16 lanes, 16B loads ----
__global__ __launch_bounds__(256) void aggregate_kernel(const _Float16* __restrict__ H,
                                                        const int* __restrict__ rs,
                                                        const int* __restrict__ ssrc,
                                                        _Float16* __restrict__ AGG) {
    int wid = (blockIdx.x * 256 + threadIdx.x) >> 6;
    int lane = threadIdx.x & 63;
    int grp = lane >> 4, l16 = lane & 15;
    int e0 = rs[wid], e1 = rs[wid + 1];
    int deg = e1 - e0;
    int q = (deg + 3) >> 2;
    int e = e0 + grp * q;
    int ge = min(e + q, e1);

    float acc[8] = {0.f, 0.f, 0.f, 0.f, 0.f, 0.f, 0.f, 0.f};
    const _Float16* __restrict__ Hc = H + l16 * 8;

    for (; e + 4 <= ge; e += 4) {
        int s0 = ssrc[e], s1 = ssrc[e + 1], s2 = ssrc[e + 2], s3 = ssrc[e + 3];
        half8 v0 = *(const half8*)(Hc + (long)s0 * HD);
        half8 v1 = *(const half8*)(Hc + (long)s1 * HD);
        half8 v2 = *(const half8*)(Hc + (long)s2 * HD);
        half8 v3 = *(const half8*)(Hc + (long)s3 * HD);
        #pragma unroll
        for (int j = 0; j < 8; ++j)
            acc[j] += ((float)v0[j] + (float)v1[j]) + ((float)v2[j] + (float)v3[j]);
    }
    for (; e < ge; ++e) {
        int s0 = ssrc[e];
        half8 v0 = *(const half8*)(Hc + (long)s0 * HD);
        #pragma unroll
        for (int j = 0; j < 8; ++j) acc[j] += (float)v0[j];
    }

    #pragma unroll
    for (int j = 0; j < 8; ++j) {
        acc[j] += __shfl_xor(acc[j], 16);
        acc[j] += __shfl_xor(acc[j], 32);
    }
    if (grp == 0) {
        float inv = 1.f / (float)max(deg, 1);
        half8 o;
        #pragma unroll
        for (int j = 0; j < 8; ++j) o[j] = (_Float16)(acc[j] * inv);
        *(half8*)(AGG + (long)wid * HD + l16 * 8) = o;
    }
}

// ---- MFMA GEMM: Y[r][c] = concat(A0,A1)[r][:] . Wt[c][:] + bias[c] ----
// STATS: column sums / sq-sums reduced in LDS then one global atomicAdd per
// column into gstats[0..127]=sum, [128..255]=sumsq (zeroed at launch start).
template <int CT, int KS, bool HAS_A1, bool A_F32, bool OUT_F32, bool STATS>
__global__ __launch_bounds__(256) void gemm_kernel(const void* __restrict__ A0v,
                                                   const _Float16* __restrict__ A1,
                                                   const _Float16* __restrict__ Wt,
                                                   const float* __restrict__ bias,
                                                   void* __restrict__ Yv,
                                                   int out_stride, int ncols,
                                                   float* __restrict__ gstats) {
    constexpr int K = KS * 32;
    int wave = threadIdx.x >> 6;
    int lane = threadIdx.x & 63;
    int quad = lane >> 4;
    int l16 = lane & 15;
    int row_base = (blockIdx.x * 4 + wave) * 32;
    bool active = row_base < N_NODES;

    __shared__ float lsum[128], lsq[128];
    if (STATS) {
        if (threadIdx.x < 128) { lsum[threadIdx.x] = 0.f; lsq[threadIdx.x] = 0.f; }
        __syncthreads();
    } else {
        if (!active) return;
    }

    floatx4 acc[2][CT];
    #pragma unroll
    for (int rt = 0; rt < 2; ++rt)
        #pragma unroll
        for (int c = 0; c < CT; ++c)
            acc[rt][c] = (floatx4){0.f, 0.f, 0.f, 0.f};

    if (active) {
        #pragma unroll
        for (int s = 0; s < KS; ++s) {
            int kk = s * 32 + quad * 8;
            half8 afrag[2];
            #pragma unroll
            for (int rt = 0; rt < 2; ++rt) {
                int r = row_base + rt * 16 + l16;
                if (r > N_NODES - 1) r = N_NODES - 1;  // clamp read, store guarded below
                if (A_F32) {
                    const float* p = (const float*)A0v + (long)r * 128 + kk;
                    floatx4 f0 = *(const floatx4*)p;
                    floatx4 f1 = *(const floatx4*)(p + 4);
                    #pragma unroll
                    for (int j = 0; j < 4; ++j) {
                        afrag[rt][j]     = (_Float16)f0[j];
                        afrag[rt][4 + j] = (_Float16)f1[j];
                    }
                } else {
                    const _Float16* p;
                    if (HAS_A1 && kk >= 128) p = A1 + (long)r * 128 + (kk - 128);
                    else                     p = (const _Float16*)A0v + (long)r * 128 + kk;
                    afrag[rt] = *(const half8*)p;
                }
            }
            #pragma unroll
            for (int c = 0; c < CT; ++c) {
                half8 bfrag = *(const half8*)(Wt + (c * 16 + l16) * K + kk);
                #pragma unroll
                for (int rt = 0; rt < 2; ++rt)
                    acc[rt][c] = __builtin_amdgcn_mfma_f32_16x16x32_f16(afrag[rt], bfrag, acc[rt][c], 0, 0, 0);
            }
        }
    }

    #pragma unroll
    for (int c = 0; c < CT; ++c) {
        int col = c * 16 + l16;
        float s_c = 0.f, q_c = 0.f;
        if (active && col < ncols) {
            float bv = bias[col];
            #pragma unroll
            for (int rt = 0; rt < 2; ++rt) {
                #pragma unroll
                for (int i = 0; i < 4; ++i) {
                    int r = row_base + rt * 16 + quad * 4 + i;
                    if (r < N_NODES) {
                        float v = acc[rt][c][i] + bv;
                        if (OUT_F32) ((float*)Yv)[(long)r * out_stride + col] = v;
                        else         ((_Float16*)Yv)[(long)r * out_stride + col] = (_Float16)v;
                        if (STATS) { s_c += v; q_c += v * v; }
                    }
                }
            }
        }
        if (STATS) {
            s_c += __shfl_xor(s_c, 16); s_c += __shfl_xor(s_c, 32);
            q_c += __shfl_xor(q_c, 16); q_c += __shfl_xor(q_c, 32);
            if (lane < 16 && active) {
                atomicAdd(&lsum[col], s_c);
                atomicAdd(&lsq[col], q_c);
            }
        }
    }

    if (STATS) {
        __syncthreads();
        if (threadIdx.x < 128) {
            atomicAdd(&gstats[threadIdx.x], lsum[threadIdx.x]);
            atomicAdd(&gstats[128 + threadIdx.x], lsq[threadIdx.x]);
        }
    }
}

// ---- BN apply: each block derives scale/shift from gstats (redundant, trivial) ----
__global__ __launch_bounds__(256) void bn_apply_kernel(const _Float16* __restrict__ Y,
                                                       const float* __restrict__ gstats,
                                                       const float* __restrict__ g,
                                                       const float* __restrict__ b,
                                                       _Float16* __restrict__ H) {
    __shared__ float sc[128], sh[128];
    if (threadIdx.x < 128) {
        int col = threadIdx.x;
        float m = gstats[col] * (1.f / (float)N_NODES);
        float v = gstats[128 + col] * (1.f / (float)N_NODES) - m * m;
        float s = g[col] * rsqrtf(v + BN_EPS);
        sc[col] = s;
        sh[col] = b[col] - m * s;
    }
    __syncthreads();
    long total = (long)N_NODES * HD / 8;
    for (long t = (long)blockIdx.x * blockDim.x + threadIdx.x; t < total;
         t += (long)gridDim.x * blockDim.x) {
        long base = t * 8;
        int col0 = (int)(base & 127);
        half8 in = *(const half8*)(Y + base);
        half8 outv;
        #pragma unroll
        for (int j = 0; j < 8; ++j) {
            float v = (float)in[j];
            float r = v * sc[col0 + j] + sh[col0 + j];
            outv[j] = (_Float16)fmaxf(r, 0.f);
        }
        *(half8*)(H + base) = outv;
    }
}

extern "C" void kernel_launch(void* const* d_in, const int* in_sizes, int n_in,
                              void* d_out, int out_size, void* d_ws, size_t ws_size,
                              hipStream_t stream) {
    (void)in_sizes; (void)n_in; (void)out_size; (void)ws_size;
    const float* x       = (const float*)d_in[0];
    const float* W_in    = (const float*)d_in[1];
    const float* b_in    = (const float*)d_in[2];
    const float* g_in    = (const float*)d_in[3];
    const float* beta_in = (const float*)d_in[4];
    const float* Wl      = (const float*)d_in[5];
    const float* bl      = (const float*)d_in[6];
    const float* Wr      = (const float*)d_in[7];
    const float* g_bn    = (const float*)d_in[8];
    const float* b_bn    = (const float*)d_in[9];
    const float* W_out   = (const float*)d_in[10];
    const float* b_out   = (const float*)d_in[11];
    const int*   ei      = (const int*)d_in[12];
    const int* esrc = ei;
    const int* edst = ei + N_EDGES;
    float* out = (float*)d_out;

    char* w = (char*)d_ws;
    auto alloc = [&](size_t bytes) -> char* {
        char* p = w; w += (bytes + 255) & ~(size_t)255; return p;
    };
    int* rs           = (int*)alloc((N_NODES + 1) * sizeof(int));  // deg -> row_start
    int* cur          = (int*)alloc(N_NODES * sizeof(int));
    int* bsum         = (int*)alloc(512 * sizeof(int));
    int* ssrc         = (int*)alloc(N_EDGES * sizeof(int));
    _Float16* Wt_in   = (_Float16*)alloc(128 * 128 * 2);
    _Float16* Wt_cat  = (_Float16*)alloc(4 * 128 * 256 * 2);
    _Float16* Wt_out  = (_Float16*)alloc(48 * 128 * 2);
    _Float16* hbuf    = (_Float16*)alloc((size_t)N_NODES * HD * 2);
    _Float16* agg     = (_Float16*)alloc((size_t)N_NODES * HD * 2);
    _Float16* ybuf    = (_Float16*)alloc((size_t)N_NODES * HD * 2);
    float* gstats     = (float*)alloc(4 * 256 * 4);   // [layer][sum128|sq128]

    hipMemsetAsync(rs, 0, (N_NODES + 1) * sizeof(int), stream);
    hipMemsetAsync(gstats, 0, 4 * 256 * 4, stream);
    prep_kernel<<<256, 256, 0, stream>>>(W_in, Wl, Wr, W_out, Wt_in, Wt_cat, Wt_out);
    hist_kernel<<<2048, 256, 0, stream>>>(edst, rs);
    scan1_kernel<<<NB, 256, 0, stream>>>(rs, bsum);
    scan2_kernel<<<1, 64, 0, stream>>>(bsum, rs);
    scan3_kernel<<<NB, 256, 0, stream>>>(rs, cur, bsum);
    scatter_kernel<<<2048, 256, 0, stream>>>(esrc, edst, cur, ssrc);

    // input layer: y = x @ W_in + b_in ; h = relu(bn(y))  (stats fused in gemm)
    gemm_kernel<8, 4, false, true, false, true><<<GB, 256, 0, stream>>>(
        x, nullptr, Wt_in, b_in, ybuf, HD, HD, gstats);
    bn_apply_kernel<<<1600, 256, 0, stream>>>(ybuf, gstats, g_in, beta_in, hbuf);

    for (int i = 0; i < NLAYERS; ++i) {
        aggregate_kernel<<<N_NODES / 4, 256, 0, stream>>>(hbuf, rs, ssrc, agg);
        if (i < NLAYERS - 1) {
            float* gs = gstats + (i + 1) * 256;
            gemm_kernel<8, 8, true, false, false, true><<<GB, 256, 0, stream>>>(
                agg, hbuf, Wt_cat + i * 128 * 256, bl + i * 128, ybuf, HD, HD, gs);
            bn_apply_kernel<<<1600, 256, 0, stream>>>(ybuf, gs, g_bn + i * 128, b_bn + i * 128, hbuf);
        } else {
            gemm_kernel<8, 8, true, false, false, false><<<GB, 256, 0, stream>>>(
                agg, hbuf, Wt_cat + i * 128 * 256, bl + i * 128, ybuf, HD, HD, nullptr);
        }
    }

    // output layer: out = h4 @ W_out + b_out  (h4 lives in ybuf, no BN on last layer)
    gemm_kernel<3, 4, false, false, true, false><<<GB, 256, 0, stream>>>(
        ybuf, nullptr, Wt_out, b_out, out, COUT, COUT, nullptr);
}

// Round 5
// 822.253 us; speedup vs baseline: 2.1364x; 1.1463x over previous
//
#include <hip/hip_runtime.h>

#define N_NODES 100000
#define N_EDGES 1600000
#define HD 128
#define NLAYERS 4
#define COUT 40
#define BN_EPS 1e-5f
#define NBUCK 782                 // buckets of 128 nodes: (100000+127)/128
#define BUCK_CAP 3072             // mean 2048, sigma ~45 -> 22-sigma margin
constexpr int GB = (N_NODES + 127) / 128;   // 782 gemm blocks

typedef _Float16 half8 __attribute__((ext_vector_type(8)));
typedef float floatx4 __attribute__((ext_vector_type(4)));

// ---- weight transpose + fp32->fp16 prep: Wt[n][k] so B-fragments are contiguous ----
__global__ void prep_kernel(const float* __restrict__ W_in,
                            const float* __restrict__ Wl,
                            const float* __restrict__ Wr,
                            const float* __restrict__ W_out,
                            _Float16* __restrict__ Wt_in,    // [128][128]
                            _Float16* __restrict__ Wt_cat,   // [4][128][256] (k<128->Wl, k>=128->Wr)
                            _Float16* __restrict__ Wt_out)   // [48][128], rows(n) >= 40 zero
{
    int tid = blockIdx.x * blockDim.x + threadIdx.x;
    int stride = gridDim.x * blockDim.x;
    for (int idx = tid; idx < 128 * 128; idx += stride) {
        int n = idx >> 7, k = idx & 127;
        Wt_in[idx] = (_Float16)W_in[k * 128 + n];
    }
    for (int idx = tid; idx < 4 * 128 * 256; idx += stride) {
        int i = idx >> 15;
        int r = idx & 32767;
        int n = r >> 8, k = r & 255;
        Wt_cat[idx] = (_Float16)((k < 128) ? Wl[i * 16384 + k * 128 + n]
                                           : Wr[i * 16384 + (k - 128) * 128 + n]);
    }
    for (int idx = tid; idx < 48 * 128; idx += stride) {
        int n = idx >> 7, k = idx & 127;
        Wt_out[idx] = (n < COUT) ? (_Float16)W_out[k * COUT + n] : (_Float16)0.f;
    }
}

// ---- CSR build, phase 1: bucket histogram (LDS-staged, ~50K global atomics) ----
__global__ __launch_bounds__(256) void bucket_hist_kernel(const int* __restrict__ edst,
                                                          int* __restrict__ bcnt) {
    __shared__ int h[NBUCK];
    for (int b = threadIdx.x; b < NBUCK; b += 256) h[b] = 0;
    __syncthreads();
    int tid = blockIdx.x * 256 + threadIdx.x;
    int stride = gridDim.x * 256;
    for (int e = tid; e < N_EDGES; e += stride)
        atomicAdd(&h[edst[e] >> 7], 1);
    __syncthreads();
    for (int b = threadIdx.x; b < NBUCK; b += 256)
        if (h[b]) atomicAdd(&bcnt[b], h[b]);
}

// ---- phase 2: one-wave exclusive scan of bucket counts -> bbase, bcur ----
__global__ void bucket_scan_kernel(const int* __restrict__ bcnt,
                                   int* __restrict__ bbase, int* __restrict__ bcur) {
    int lane = threadIdx.x;
    int run = 0;
    for (int base = 0; base < NBUCK; base += 64) {
        int i = base + lane;
        int orig = (i < NBUCK) ? bcnt[i] : 0;
        int v = orig;
        #pragma unroll
        for (int off = 1; off < 64; off <<= 1) {
            int t = __shfl_up(v, off);
            if (lane >= off) v += t;
        }
        int total = __shfl(v, 63);
        int excl = v - orig + run;
        if (i < NBUCK) { bbase[i] = excl; bcur[i] = excl; }
        run += total;
    }
    if (lane == 0) bbase[NBUCK] = run;   // == N_EDGES
}

// ---- phase 3: bucketed scatter; rank via LDS atomics, 1 global atomic/bucket/tile ----
#define SCAT_T 16
__global__ __launch_bounds__(512) void bucket_scatter_kernel(const int* __restrict__ esrc,
                                                             const int* __restrict__ edst,
                                                             int* __restrict__ bcur,
                                                             int* __restrict__ bedges) {
    __shared__ int cnt[NBUCK], gpos[NBUCK];
    long base = (long)blockIdx.x * (512 * SCAT_T);
    for (int b = threadIdx.x; b < NBUCK; b += 512) cnt[b] = 0;
    __syncthreads();
    int srcs[SCAT_T], locs[SCAT_T], rnk[SCAT_T], bks[SCAT_T];
    #pragma unroll
    for (int j = 0; j < SCAT_T; ++j) {
        long e = base + j * 512 + threadIdx.x;
        if (e < N_EDGES) {
            int d = edst[e];
            srcs[j] = esrc[e];
            bks[j] = d >> 7;
            locs[j] = d & 127;
            rnk[j] = atomicAdd(&cnt[bks[j]], 1);
        } else bks[j] = -1;
    }
    __syncthreads();
    for (int b = threadIdx.x; b < NBUCK; b += 512) {
        int c = cnt[b];
        gpos[b] = c ? atomicAdd(&bcur[b], c) : 0;
    }
    __syncthreads();
    #pragma unroll
    for (int j = 0; j < SCAT_T; ++j)
        if (bks[j] >= 0)
            bedges[gpos[bks[j]] + rnk[j]] = (locs[j] << 17) | srcs[j];
}

// ---- phase 4: per-bucket LDS counting sort -> rs (coalesced) + ssrc ----
__global__ __launch_bounds__(256) void bucket_sort_kernel(const int* __restrict__ bedges,
                                                          const int* __restrict__ bbase,
                                                          int* __restrict__ rs,
                                                          int* __restrict__ ssrc) {
    __shared__ int lsrc[BUCK_CAP];
    __shared__ int h[128], hin[128], lcur[128];
    int b = blockIdx.x;
    int s = bbase[b];
    int n = bbase[b + 1] - s;
    if (n > BUCK_CAP) n = BUCK_CAP;   // statistically impossible; LDS safety
    if (threadIdx.x < 128) h[threadIdx.x] = 0;
    __syncthreads();
    for (int i = threadIdx.x; i < n; i += 256) {
        int v = bedges[s + i];
        lsrc[i] = v;
        atomicAdd(&h[v >> 17], 1);
    }
    __syncthreads();
    if (threadIdx.x < 128) hin[threadIdx.x] = h[threadIdx.x];
    __syncthreads();
    #pragma unroll
    for (int off = 1; off < 128; off <<= 1) {   // Hillis-Steele inclusive scan
        int t = 0;
        if (threadIdx.x < 128 && (int)threadIdx.x >= off) t = h[threadIdx.x - off];
        __syncthreads();
        if (threadIdx.x < 128) h[threadIdx.x] += t;
        __syncthreads();
    }
    if (threadIdx.x < 128) {
        int excl = h[threadIdx.x] - hin[threadIdx.x];
        lcur[threadIdx.x] = excl;
        int node = b * 128 + threadIdx.x;
        if (node < N_NODES) rs[node] = s + excl;
    }
    if (b == NBUCK - 1 && threadIdx.x == 0) rs[N_NODES] = bbase[NBUCK];
    __syncthreads();
    for (int i = threadIdx.x; i < n; i += 256) {
        int v = lsrc[i];
        int r = atomicAdd(&lcur[v >> 17], 1);
        ssrc[s + r] = v & 0x1FFFF;   // scattered only within this bucket's 12 KB
    }
}

// ---- mean aggregation: one wave per dst node, 4 groups x 16 lanes, 16B loads ----
__global__ __launch_bounds__(256) void aggregate_kernel(const _Float16* __restrict__ H,
                                                        const int* __restrict__ rs,
                                                        const int* __restrict__ ssrc,
                                                        _Float16* __restrict__ AGG) {
    int wid = (blockIdx.x * 256 + threadIdx.x) >> 6;
    int lane = threadIdx.x & 63;
    int grp = lane >> 4, l16 = lane & 15;
    int e0 = rs[wid], e1 = rs[wid + 1];
    int deg = e1 - e0;
    int q = (deg + 3) >> 2;
    int e = e0 + grp * q;
    int ge = min(e + q, e1);

    float acc[8] = {0.f, 0.f, 0.f, 0.f, 0.f, 0.f, 0.f, 0.f};
    const _Float16* __restrict__ Hc = H + l16 * 8;

    for (; e + 4 <= ge; e += 4) {
        int s0 = ssrc[e], s1 = ssrc[e + 1], s2 = ssrc[e + 2], s3 = ssrc[e + 3];
        half8 v0 = *(const half8*)(Hc + (long)s0 * HD);
        half8 v1 = *(const half8*)(Hc + (long)s1 * HD);
        half8 v2 = *(const half8*)(Hc + (long)s2 * HD);
        half8 v3 = *(const half8*)(Hc + (long)s3 * HD);
        #pragma unroll
        for (int j = 0; j < 8; ++j)
            acc[j] += ((float)v0[j] + (float)v1[j]) + ((float)v2[j] + (float)v3[j]);
    }
    for (; e < ge; ++e) {
        int s0 = ssrc[e];
        half8 v0 = *(const half8*)(Hc + (long)s0 * HD);
        #pragma unroll
        for (int j = 0; j < 8; ++j) acc[j] += (float)v0[j];
    }

    #pragma unroll
    for (int j = 0; j < 8; ++j) {
        acc[j] += __shfl_xor(acc[j], 16);
        acc[j] += __shfl_xor(acc[j], 32);
    }
    if (grp == 0) {
        float inv = 1.f / (float)max(deg, 1);
        half8 o;
        #pragma unroll
        for (int j = 0; j < 8; ++j) o[j] = (_Float16)(acc[j] * inv);
        *(half8*)(AGG + (long)wid * HD + l16 * 8) = o;
    }
}

// ---- MFMA GEMM: Y[r][c] = concat(A0,A1)[r][:] . Wt[c][:] + bias[c] ----
// STATS: column sums / sq-sums reduced in LDS then one global atomicAdd per
// column into gstats[0..127]=sum, [128..255]=sumsq (zeroed at launch start).
template <int CT, int KS, bool HAS_A1, bool A_F32, bool OUT_F32, bool STATS>
__global__ __launch_bounds__(256) void gemm_kernel(const void* __restrict__ A0v,
                                                   const _Float16* __restrict__ A1,
                                                   const _Float16* __restrict__ Wt,
                                                   const float* __restrict__ bias,
                                                   void* __restrict__ Yv,
                                                   int out_stride, int ncols,
                                                   float* __restrict__ gstats) {
    constexpr int K = KS * 32;
    int wave = threadIdx.x >> 6;
    int lane = threadIdx.x & 63;
    int quad = lane >> 4;
    int l16 = lane & 15;
    int row_base = (blockIdx.x * 4 + wave) * 32;
    bool active = row_base < N_NODES;

    __shared__ float lsum[128], lsq[128];
    if (STATS) {
        if (threadIdx.x < 128) { lsum[threadIdx.x] = 0.f; lsq[threadIdx.x] = 0.f; }
        __syncthreads();
    } else {
        if (!active) return;
    }

    floatx4 acc[2][CT];
    #pragma unroll
    for (int rt = 0; rt < 2; ++rt)
        #pragma unroll
        for (int c = 0; c < CT; ++c)
            acc[rt][c] = (floatx4){0.f, 0.f, 0.f, 0.f};

    if (active) {
        #pragma unroll
        for (int s = 0; s < KS; ++s) {
            int kk = s * 32 + quad * 8;
            half8 afrag[2];
            #pragma unroll
            for (int rt = 0; rt < 2; ++rt) {
                int r = row_base + rt * 16 + l16;
                if (r > N_NODES - 1) r = N_NODES - 1;  // clamp read, store guarded below
                if (A_F32) {
                    const float* p = (const float*)A0v + (long)r * 128 + kk;
                    floatx4 f0 = *(const floatx4*)p;
                    floatx4 f1 = *(const floatx4*)(p + 4);
                    #pragma unroll
                    for (int j = 0; j < 4; ++j) {
                        afrag[rt][j]     = (_Float16)f0[j];
                        afrag[rt][4 + j] = (_Float16)f1[j];
                    }
                } else {
                    const _Float16* p;
                    if (HAS_A1 && kk >= 128) p = A1 + (long)r * 128 + (kk - 128);
                    else                     p = (const _Float16*)A0v + (long)r * 128 + kk;
                    afrag[rt] = *(const half8*)p;
                }
            }
            #pragma unroll
            for (int c = 0; c < CT; ++c) {
                half8 bfrag = *(const half8*)(Wt + (c * 16 + l16) * K + kk);
                #pragma unroll
                for (int rt = 0; rt < 2; ++rt)
                    acc[rt][c] = __builtin_amdgcn_mfma_f32_16x16x32_f16(afrag[rt], bfrag, acc[rt][c], 0, 0, 0);
            }
        }
    }

    #pragma unroll
    for (int c = 0; c < CT; ++c) {
        int col = c * 16 + l16;
        float s_c = 0.f, q_c = 0.f;
        if (active && col < ncols) {
            float bv = bias[col];
            #pragma unroll
            for (int rt = 0; rt < 2; ++rt) {
                #pragma unroll
                for (int i = 0; i < 4; ++i) {
                    int r = row_base + rt * 16 + quad * 4 + i;
                    if (r < N_NODES) {
                        float v = acc[rt][c][i] + bv;
                        if (OUT_F32) ((float*)Yv)[(long)r * out_stride + col] = v;
                        else         ((_Float16*)Yv)[(long)r * out_stride + col] = (_Float16)v;
                        if (STATS) { s_c += v; q_c += v * v; }
                    }
                }
            }
        }
        if (STATS) {
            s_c += __shfl_xor(s_c, 16); s_c += __shfl_xor(s_c, 32);
            q_c += __shfl_xor(q_c, 16); q_c += __shfl_xor(q_c, 32);
            if (lane < 16 && active) {
                atomicAdd(&lsum[col], s_c);
                atomicAdd(&lsq[col], q_c);
            }
        }
    }

    if (STATS) {
        __syncthreads();
        if (threadIdx.x < 128) {
            atomicAdd(&gstats[threadIdx.x], lsum[threadIdx.x]);
            atomicAdd(&gstats[128 + threadIdx.x], lsq[threadIdx.x]);
        }
    }
}

// ---- BN apply: each block derives scale/shift from gstats (redundant, trivial) ----
__global__ __launch_bounds__(256) void bn_apply_kernel(const _Float16* __restrict__ Y,
                                                       const float* __restrict__ gstats,
                                                       const float* __restrict__ g,
                                                       const float* __restrict__ b,
                                                       _Float16* __restrict__ H) {
    __shared__ float sc[128], sh[128];
    if (threadIdx.x < 128) {
        int col = threadIdx.x;
        float m = gstats[col] * (1.f / (float)N_NODES);
        float v = gstats[128 + col] * (1.f / (float)N_NODES) - m * m;
        float s = g[col] * rsqrtf(v + BN_EPS);
        sc[col] = s;
        sh[col] = b[col] - m * s;
    }
    __syncthreads();
    long total = (long)N_NODES * HD / 8;
    for (long t = (long)blockIdx.x * blockDim.x + threadIdx.x; t < total;
         t += (long)gridDim.x * blockDim.x) {
        long base = t * 8;
        int col0 = (int)(base & 127);
        half8 in = *(const half8*)(Y + base);
        half8 outv;
        #pragma unroll
        for (int j = 0; j < 8; ++j) {
            float v = (float)in[j];
            float r = v * sc[col0 + j] + sh[col0 + j];
            outv[j] = (_Float16)fmaxf(r, 0.f);
        }
        *(half8*)(H + base) = outv;
    }
}

extern "C" void kernel_launch(void* const* d_in, const int* in_sizes, int n_in,
                              void* d_out, int out_size, void* d_ws, size_t ws_size,
                              hipStream_t stream) {
    (void)in_sizes; (void)n_in; (void)out_size; (void)ws_size;
    const float* x       = (const float*)d_in[0];
    const float* W_in    = (const float*)d_in[1];
    const float* b_in    = (const float*)d_in[2];
    const float* g_in    = (const float*)d_in[3];
    const float* beta_in = (const float*)d_in[4];
    const float* Wl      = (const float*)d_in[5];
    const float* bl      = (const float*)d_in[6];
    const float* Wr      = (const float*)d_in[7];
    const float* g_bn    = (const float*)d_in[8];
    const float* b_bn    = (const float*)d_in[9];
    const float* W_out   = (const float*)d_in[10];
    const float* b_out   = (const float*)d_in[11];
    const int*   ei      = (const int*)d_in[12];
    const int* esrc = ei;
    const int* edst = ei + N_EDGES;
    float* out = (float*)d_out;

    char* w = (char*)d_ws;
    auto alloc = [&](size_t bytes) -> char* {
        char* p = w; w += (bytes + 255) & ~(size_t)255; return p;
    };
    int* rs           = (int*)alloc((N_NODES + 1) * sizeof(int));
    int* bcnt         = (int*)alloc((NBUCK + 1) * sizeof(int));
    int* bbase        = (int*)alloc((NBUCK + 1) * sizeof(int));
    int* bcur         = (int*)alloc(NBUCK * sizeof(int));
    int* ssrc         = (int*)alloc(N_EDGES * sizeof(int));
    _Float16* Wt_in   = (_Float16*)alloc(128 * 128 * 2);
    _Float16* Wt_cat  = (_Float16*)alloc(4 * 128 * 256 * 2);
    _Float16* Wt_out  = (_Float16*)alloc(48 * 128 * 2);
    _Float16* hbuf    = (_Float16*)alloc((size_t)N_NODES * HD * 2);
    _Float16* agg     = (_Float16*)alloc((size_t)N_NODES * HD * 2);
    _Float16* ybuf    = (_Float16*)alloc((size_t)N_NODES * HD * 2);
    float* gstats     = (float*)alloc(4 * 256 * 4);   // [layer][sum128|sq128]
    int* bedges       = (int*)agg;   // alias: dead before first aggregate

    hipMemsetAsync(bcnt, 0, (NBUCK + 1) * sizeof(int), stream);
    hipMemsetAsync(gstats, 0, 4 * 256 * 4, stream);
    prep_kernel<<<256, 256, 0, stream>>>(W_in, Wl, Wr, W_out, Wt_in, Wt_cat, Wt_out);
    bucket_hist_kernel<<<64, 256, 0, stream>>>(edst, bcnt);
    bucket_scan_kernel<<<1, 64, 0, stream>>>(bcnt, bbase, bcur);
    bucket_scatter_kernel<<<(N_EDGES + 8191) / 8192, 512, 0, stream>>>(esrc, edst, bcur, bedges);
    bucket_sort_kernel<<<NBUCK, 256, 0, stream>>>(bedges, bbase, rs, ssrc);

    // input layer: y = x @ W_in + b_in ; h = relu(bn(y))  (stats fused in gemm)
    gemm_kernel<8, 4, false, true, false, true><<<GB, 256, 0, stream>>>(
        x, nullptr, Wt_in, b_in, ybuf, HD, HD, gstats);
    bn_apply_kernel<<<1600, 256, 0, stream>>>(ybuf, gstats, g_in, beta_in, hbuf);

    for (int i = 0; i < NLAYERS; ++i) {
        aggregate_kernel<<<N_NODES / 4, 256, 0, stream>>>(hbuf, rs, ssrc, agg);
        if (i < NLAYERS - 1) {
            float* gs = gstats + (i + 1) * 256;
            gemm_kernel<8, 8, true, false, false, true><<<GB, 256, 0, stream>>>(
                agg, hbuf, Wt_cat + i * 128 * 256, bl + i * 128, ybuf, HD, HD, gs);
            bn_apply_kernel<<<1600, 256, 0, stream>>>(ybuf, gs, g_bn + i * 128, b_bn + i * 128, hbuf);
        } else {
            gemm_kernel<8, 8, true, false, false, false><<<GB, 256, 0, stream>>>(
                agg, hbuf, Wt_cat + i * 128 * 256, bl + i * 128, ybuf, HD, HD, nullptr);
        }
    }

    // output layer: out = h4 @ W_out + b_out  (h4 lives in ybuf, no BN on last layer)
    gemm_kernel<3, 4, false, false, true, false><<<GB, 256, 0, stream>>>(
        ybuf, nullptr, Wt_out, b_out, out, COUT, COUT, nullptr);
}

// Round 6
// 661.229 us; speedup vs baseline: 2.6567x; 1.2435x over previous
//
#include <hip/hip_runtime.h>

#define N_NODES 100000
#define N_EDGES 1600000
#define HD 128
#define NLAYERS 4
#define COUT 40
#define BN_EPS 1e-5f
#define NBUCK 782                 // buckets of 128 nodes: (100000+127)/128
#define BUCK_CAP 3072             // mean 2048, sigma ~45 -> 22-sigma margin
constexpr int GB = (N_NODES + 127) / 128;   // 782 gemm blocks

typedef _Float16 half8 __attribute__((ext_vector_type(8)));
typedef float floatx4 __attribute__((ext_vector_type(4)));

// ---- weight transpose + fp32->fp16 prep: Wt[n][k] so B-fragments are contiguous ----
__global__ void prep_kernel(const float* __restrict__ W_in,
                            const float* __restrict__ Wl,
                            const float* __restrict__ Wr,
                            const float* __restrict__ W_out,
                            _Float16* __restrict__ Wt_in,    // [128][128]
                            _Float16* __restrict__ Wt_cat,   // [4][128][256] (k<128->Wl, k>=128->Wr)
                            _Float16* __restrict__ Wt_out)   // [48][128], rows(n) >= 40 zero
{
    int tid = blockIdx.x * blockDim.x + threadIdx.x;
    int stride = gridDim.x * blockDim.x;
    for (int idx = tid; idx < 128 * 128; idx += stride) {
        int n = idx >> 7, k = idx & 127;
        Wt_in[idx] = (_Float16)W_in[k * 128 + n];
    }
    for (int idx = tid; idx < 4 * 128 * 256; idx += stride) {
        int i = idx >> 15;
        int r = idx & 32767;
        int n = r >> 8, k = r & 255;
        Wt_cat[idx] = (_Float16)((k < 128) ? Wl[i * 16384 + k * 128 + n]
                                           : Wr[i * 16384 + (k - 128) * 128 + n]);
    }
    for (int idx = tid; idx < 48 * 128; idx += stride) {
        int n = idx >> 7, k = idx & 127;
        Wt_out[idx] = (n < COUT) ? (_Float16)W_out[k * COUT + n] : (_Float16)0.f;
    }
}

// ---- CSR build, phase 1: bucket histogram (LDS-staged, ~50K global atomics) ----
__global__ __launch_bounds__(256) void bucket_hist_kernel(const int* __restrict__ edst,
                                                          int* __restrict__ bcnt) {
    __shared__ int h[NBUCK];
    for (int b = threadIdx.x; b < NBUCK; b += 256) h[b] = 0;
    __syncthreads();
    int tid = blockIdx.x * 256 + threadIdx.x;
    int stride = gridDim.x * 256;
    for (int e = tid; e < N_EDGES; e += stride)
        atomicAdd(&h[edst[e] >> 7], 1);
    __syncthreads();
    for (int b = threadIdx.x; b < NBUCK; b += 256)
        if (h[b]) atomicAdd(&bcnt[b], h[b]);
}

// ---- phase 2: one-wave exclusive scan of bucket counts -> bbase, bcur ----
__global__ void bucket_scan_kernel(const int* __restrict__ bcnt,
                                   int* __restrict__ bbase, int* __restrict__ bcur) {
    int lane = threadIdx.x;
    int run = 0;
    for (int base = 0; base < NBUCK; base += 64) {
        int i = base + lane;
        int orig = (i < NBUCK) ? bcnt[i] : 0;
        int v = orig;
        #pragma unroll
        for (int off = 1; off < 64; off <<= 1) {
            int t = __shfl_up(v, off);
            if (lane >= off) v += t;
        }
        int total = __shfl(v, 63);
        int excl = v - orig + run;
        if (i < NBUCK) { bbase[i] = excl; bcur[i] = excl; }
        run += total;
    }
    if (lane == 0) bbase[NBUCK] = run;   // == N_EDGES
}

// ---- phase 3: bucketed scatter; rank via LDS atomics, 1 global atomic/bucket/tile ----
#define SCAT_T 16
__global__ __launch_bounds__(512) void bucket_scatter_kernel(const int* __restrict__ esrc,
                                                             const int* __restrict__ edst,
                                                             int* __restrict__ bcur,
                                                             int* __restrict__ bedges) {
    __shared__ int cnt[NBUCK], gpos[NBUCK];
    long base = (long)blockIdx.x * (512 * SCAT_T);
    for (int b = threadIdx.x; b < NBUCK; b += 512) cnt[b] = 0;
    __syncthreads();
    int srcs[SCAT_T], locs[SCAT_T], rnk[SCAT_T], bks[SCAT_T];
    #pragma unroll
    for (int j = 0; j < SCAT_T; ++j) {
        long e = base + j * 512 + threadIdx.x;
        if (e < N_EDGES) {
            int d = edst[e];
            srcs[j] = esrc[e];
            bks[j] = d >> 7;
            locs[j] = d & 127;
            rnk[j] = atomicAdd(&cnt[bks[j]], 1);
        } else bks[j] = -1;
    }
    __syncthreads();
    for (int b = threadIdx.x; b < NBUCK; b += 512) {
        int c = cnt[b];
        gpos[b] = c ? atomicAdd(&bcur[b], c) : 0;
    }
    __syncthreads();
    #pragma unroll
    for (int j = 0; j < SCAT_T; ++j)
        if (bks[j] >= 0)
            bedges[gpos[bks[j]] + rnk[j]] = (locs[j] << 17) | srcs[j];
}

// ---- phase 4: per-bucket LDS counting sort -> rs (coalesced) + ssrc ----
__global__ __launch_bounds__(256) void bucket_sort_kernel(const int* __restrict__ bedges,
                                                          const int* __restrict__ bbase,
                                                          int* __restrict__ rs,
                                                          int* __restrict__ ssrc) {
    __shared__ int lsrc[BUCK_CAP];
    __shared__ int h[128], hin[128], lcur[128];
    int b = blockIdx.x;
    int s = bbase[b];
    int n = bbase[b + 1] - s;
    if (n > BUCK_CAP) n = BUCK_CAP;   // statistically impossible; LDS safety
    if (threadIdx.x < 128) h[threadIdx.x] = 0;
    __syncthreads();
    for (int i = threadIdx.x; i < n; i += 256) {
        int v = bedges[s + i];
        lsrc[i] = v;
        atomicAdd(&h[v >> 17], 1);
    }
    __syncthreads();
    if (threadIdx.x < 128) hin[threadIdx.x] = h[threadIdx.x];
    __syncthreads();
    #pragma unroll
    for (int off = 1; off < 128; off <<= 1) {   // Hillis-Steele inclusive scan
        int t = 0;
        if (threadIdx.x < 128 && (int)threadIdx.x >= off) t = h[threadIdx.x - off];
        __syncthreads();
        if (threadIdx.x < 128) h[threadIdx.x] += t;
        __syncthreads();
    }
    if (threadIdx.x < 128) {
        int excl = h[threadIdx.x] - hin[threadIdx.x];
        lcur[threadIdx.x] = excl;
        int node = b * 128 + threadIdx.x;
        if (node < N_NODES) rs[node] = s + excl;
    }
    if (b == NBUCK - 1 && threadIdx.x == 0) rs[N_NODES] = bbase[NBUCK];
    __syncthreads();
    for (int i = threadIdx.x; i < n; i += 256) {
        int v = lsrc[i];
        int r = atomicAdd(&lcur[v >> 17], 1);
        ssrc[s + r] = v & 0x1FFFF;   // scattered only within this bucket's 12 KB
    }
}

// ---- mean aggregation: one wave per dst node, 4 groups x 16 lanes, 16B loads ----
__global__ __launch_bounds__(256) void aggregate_kernel(const _Float16* __restrict__ H,
                                                        const int* __restrict__ rs,
                                                        const int* __restrict__ ssrc,
                                                        _Float16* __restrict__ AGG) {
    int wid = (blockIdx.x * 256 + threadIdx.x) >> 6;
    int lane = threadIdx.x & 63;
    int grp = lane >> 4, l16 = lane & 15;
    int e0 = rs[wid], e1 = rs[wid + 1];
    int deg = e1 - e0;
    int q = (deg + 3) >> 2;
    int e = e0 + grp * q;
    int ge = min(e + q, e1);

    float acc[8] = {0.f, 0.f, 0.f, 0.f, 0.f, 0.f, 0.f, 0.f};
    const _Float16* __restrict__ Hc = H + l16 * 8;

    for (; e + 4 <= ge; e += 4) {
        int s0 = ssrc[e], s1 = ssrc[e + 1], s2 = ssrc[e + 2], s3 = ssrc[e + 3];
        half8 v0 = *(const half8*)(Hc + (long)s0 * HD);
        half8 v1 = *(const half8*)(Hc + (long)s1 * HD);
        half8 v2 = *(const half8*)(Hc + (long)s2 * HD);
        half8 v3 = *(const half8*)(Hc + (long)s3 * HD);
        #pragma unroll
        for (int j = 0; j < 8; ++j)
            acc[j] += ((float)v0[j] + (float)v1[j]) + ((float)v2[j] + (float)v3[j]);
    }
    for (; e < ge; ++e) {
        int s0 = ssrc[e];
        half8 v0 = *(const half8*)(Hc + (long)s0 * HD);
        #pragma unroll
        for (int j = 0; j < 8; ++j) acc[j] += (float)v0[j];
    }

    #pragma unroll
    for (int j = 0; j < 8; ++j) {
        acc[j] += __shfl_xor(acc[j], 16);
        acc[j] += __shfl_xor(acc[j], 32);
    }
    if (grp == 0) {
        float inv = 1.f / (float)max(deg, 1);
        half8 o;
        #pragma unroll
        for (int j = 0; j < 8; ++j) o[j] = (_Float16)(acc[j] * inv);
        *(half8*)(AGG + (long)wid * HD + l16 * 8) = o;
    }
}

// ---- MFMA GEMM: Y[r][c] = concat(A0,A1)[r][:] . Wt[c][:] + bias[c] ----
// B staged in LDS per block in fragment order [s][c][quad][l16][8]: each
// B-fragment is one conflict-free ds_read_b128 (consecutive lanes 16 B apart).
// K chunked x128 so LDS stays <= 32 KB. STATS: column sums/sq-sums in LDS
// (overlaid on B-buffer after compute), one global atomicAdd per column.
template <int CT, int KS, bool HAS_A1, bool A_F32, bool OUT_F32, bool STATS>
__global__ __launch_bounds__(256, 2) void gemm_kernel(const void* __restrict__ A0v,
                                                      const _Float16* __restrict__ A1,
                                                      const _Float16* __restrict__ Wt,
                                                      const float* __restrict__ bias,
                                                      void* __restrict__ Yv,
                                                      int out_stride, int ncols,
                                                      float* __restrict__ gstats) {
    constexpr int K = KS * 32;
    constexpr int KSC = (KS > 4) ? 4 : KS;              // K-chunk = KSC*32 <= 128
    __shared__ _Float16 bsm[KSC * 32 * CT * 16];        // <= 32 KB
    int wave = threadIdx.x >> 6;
    int lane = threadIdx.x & 63;
    int quad = lane >> 4;
    int l16 = lane & 15;
    int row_base = (blockIdx.x * 4 + wave) * 32;
    bool active = row_base < N_NODES;

    floatx4 acc[2][CT];
    #pragma unroll
    for (int rt = 0; rt < 2; ++rt)
        #pragma unroll
        for (int c = 0; c < CT; ++c)
            acc[rt][c] = (floatx4){0.f, 0.f, 0.f, 0.f};

    for (int ch = 0; ch < KS; ch += KSC) {
        if (ch) __syncthreads();   // previous chunk fully consumed
        // stage chunk: element (n, ko) -> lds frag slot; consecutive tid ->
        // consecutive l16 (16B apart) -> conflict-free ds_write_b128
        for (int i = threadIdx.x; i < KSC * CT * 64; i += 256) {
            int n = i % (CT * 16);
            int ko = i / (CT * 16);                      // octet index in chunk
            half8 v = *(const half8*)(Wt + n * K + (ch * 4 + ko) * 8);
            int slot = (((ko >> 2) * CT + (n >> 4)) * 4 + (ko & 3)) * 16 + (n & 15);
            *(half8*)(bsm + slot * 8) = v;
        }
        __syncthreads();
        if (active) {
            #pragma unroll
            for (int s2 = 0; s2 < KSC; ++s2) {
                int s = ch + s2;
                int kk = s * 32 + quad * 8;
                half8 afrag[2];
                #pragma unroll
                for (int rt = 0; rt < 2; ++rt) {
                    int r = row_base + rt * 16 + l16;
                    if (r > N_NODES - 1) r = N_NODES - 1;  // clamp read, store guarded below
                    if (A_F32) {
                        const float* p = (const float*)A0v + (long)r * 128 + kk;
                        floatx4 f0 = *(const floatx4*)p;
                        floatx4 f1 = *(const floatx4*)(p + 4);
                        #pragma unroll
                        for (int j = 0; j < 4; ++j) {
                            afrag[rt][j]     = (_Float16)f0[j];
                            afrag[rt][4 + j] = (_Float16)f1[j];
                        }
                    } else {
                        const _Float16* p;
                        if (HAS_A1 && kk >= 128) p = A1 + (long)r * 128 + (kk - 128);
                        else                     p = (const _Float16*)A0v + (long)r * 128 + kk;
                        afrag[rt] = *(const half8*)p;
                    }
                }
                #pragma unroll
                for (int c = 0; c < CT; ++c) {
                    half8 bfrag = *(const half8*)(bsm + ((s2 * CT + c) * 64 + lane) * 8);
                    #pragma unroll
                    for (int rt = 0; rt < 2; ++rt)
                        acc[rt][c] = __builtin_amdgcn_mfma_f32_16x16x32_f16(afrag[rt], bfrag, acc[rt][c], 0, 0, 0);
                }
            }
        }
    }

    float* lsum = (float*)bsm;      // overlay stats on B-buffer (done with it)
    float* lsq  = lsum + 128;
    if (STATS) {
        __syncthreads();
        if (threadIdx.x < 128) { lsum[threadIdx.x] = 0.f; lsq[threadIdx.x] = 0.f; }
        __syncthreads();
    } else {
        if (!active) return;
    }

    #pragma unroll
    for (int c = 0; c < CT; ++c) {
        int col = c * 16 + l16;
        float s_c = 0.f, q_c = 0.f;
        if (active && col < ncols) {
            float bv = bias[col];
            #pragma unroll
            for (int rt = 0; rt < 2; ++rt) {
                #pragma unroll
                for (int i = 0; i < 4; ++i) {
                    int r = row_base + rt * 16 + quad * 4 + i;
                    if (r < N_NODES) {
                        float v = acc[rt][c][i] + bv;
                        if (OUT_F32) ((float*)Yv)[(long)r * out_stride + col] = v;
                        else         ((_Float16*)Yv)[(long)r * out_stride + col] = (_Float16)v;
                        if (STATS) { s_c += v; q_c += v * v; }
                    }
                }
            }
        }
        if (STATS) {
            s_c += __shfl_xor(s_c, 16); s_c += __shfl_xor(s_c, 32);
            q_c += __shfl_xor(q_c, 16); q_c += __shfl_xor(q_c, 32);
            if (lane < 16 && active) {
                atomicAdd(&lsum[col], s_c);
                atomicAdd(&lsq[col], q_c);
            }
        }
    }

    if (STATS) {
        __syncthreads();
        if (threadIdx.x < 128) {
            atomicAdd(&gstats[threadIdx.x], lsum[threadIdx.x]);
            atomicAdd(&gstats[128 + threadIdx.x], lsq[threadIdx.x]);
        }
    }
}

// ---- BN apply: each block derives scale/shift from gstats (redundant, trivial) ----
__global__ __launch_bounds__(256) void bn_apply_kernel(const _Float16* __restrict__ Y,
                                                       const float* __restrict__ gstats,
                                                       const float* __restrict__ g,
                                                       const float* __restrict__ b,
                                                       _Float16* __restrict__ H) {
    __shared__ float sc[128], sh[128];
    if (threadIdx.x < 128) {
        int col = threadIdx.x;
        float m = gstats[col] * (1.f / (float)N_NODES);
        float v = gstats[128 + col] * (1.f / (float)N_NODES) - m * m;
        float s = g[col] * rsqrtf(v + BN_EPS);
        sc[col] = s;
        sh[col] = b[col] - m * s;
    }
    __syncthreads();
    long total = (long)N_NODES * HD / 8;
    for (long t = (long)blockIdx.x * blockDim.x + threadIdx.x; t < total;
         t += (long)gridDim.x * blockDim.x) {
        long base = t * 8;
        int col0 = (int)(base & 127);
        half8 in = *(const half8*)(Y + base);
        half8 outv;
        #pragma unroll
        for (int j = 0; j < 8; ++j) {
            float v = (float)in[j];
            float r = v * sc[col0 + j] + sh[col0 + j];
            outv[j] = (_Float16)fmaxf(r, 0.f);
        }
        *(half8*)(H + base) = outv;
    }
}

extern "C" void kernel_launch(void* const* d_in, const int* in_sizes, int n_in,
                              void* d_out, int out_size, void* d_ws, size_t ws_size,
                              hipStream_t stream) {
    (void)in_sizes; (void)n_in; (void)out_size; (void)ws_size;
    const float* x       = (const float*)d_in[0];
    const float* W_in    = (const float*)d_in[1];
    const float* b_in    = (const float*)d_in[2];
    const float* g_in    = (const float*)d_in[3];
    const float* beta_in = (const float*)d_in[4];
    const float* Wl      = (const float*)d_in[5];
    const float* bl      = (const float*)d_in[6];
    const float* Wr      = (const float*)d_in[7];
    const float* g_bn    = (const float*)d_in[8];
    const float* b_bn    = (const float*)d_in[9];
    const float* W_out   = (const float*)d_in[10];
    const float* b_out   = (const float*)d_in[11];
    const int*   ei      = (const int*)d_in[12];
    const int* esrc = ei;
    const int* edst = ei + N_EDGES;
    float* out = (float*)d_out;

    char* w = (char*)d_ws;
    auto alloc = [&](size_t bytes) -> char* {
        char* p = w; w += (bytes + 255) & ~(size_t)255; return p;
    };
    int* rs           = (int*)alloc((N_NODES + 1) * sizeof(int));
    int* bcnt         = (int*)alloc((NBUCK + 1) * sizeof(int));
    int* bbase        = (int*)alloc((NBUCK + 1) * sizeof(int));
    int* bcur         = (int*)alloc(NBUCK * sizeof(int));
    int* ssrc         = (int*)alloc(N_EDGES * sizeof(int));
    _Float16* Wt_in   = (_Float16*)alloc(128 * 128 * 2);
    _Float16* Wt_cat  = (_Float16*)alloc(4 * 128 * 256 * 2);
    _Float16* Wt_out  = (_Float16*)alloc(48 * 128 * 2);
    _Float16* hbuf    = (_Float16*)alloc((size_t)N_NODES * HD * 2);
    _Float16* agg     = (_Float16*)alloc((size_t)N_NODES * HD * 2);
    _Float16* ybuf    = (_Float16*)alloc((size_t)N_NODES * HD * 2);
    float* gstats     = (float*)alloc(4 * 256 * 4);   // [layer][sum128|sq128]
    int* bedges       = (int*)agg;   // alias: dead before first aggregate

    hipMemsetAsync(bcnt, 0, (NBUCK + 1) * sizeof(int), stream);
    hipMemsetAsync(gstats, 0, 4 * 256 * 4, stream);
    prep_kernel<<<256, 256, 0, stream>>>(W_in, Wl, Wr, W_out, Wt_in, Wt_cat, Wt_out);
    bucket_hist_kernel<<<64, 256, 0, stream>>>(edst, bcnt);
    bucket_scan_kernel<<<1, 64, 0, stream>>>(bcnt, bbase, bcur);
    bucket_scatter_kernel<<<(N_EDGES + 8191) / 8192, 512, 0, stream>>>(esrc, edst, bcur, bedges);
    bucket_sort_kernel<<<NBUCK, 256, 0, stream>>>(bedges, bbase, rs, ssrc);

    // input layer: y = x @ W_in + b_in ; h = relu(bn(y))  (stats fused in gemm)
    gemm_kernel<8, 4, false, true, false, true><<<GB, 256, 0, stream>>>(
        x, nullptr, Wt_in, b_in, ybuf, HD, HD, gstats);
    bn_apply_kernel<<<1600, 256, 0, stream>>>(ybuf, gstats, g_in, beta_in, hbuf);

    for (int i = 0; i < NLAYERS; ++i) {
        aggregate_kernel<<<N_NODES / 4, 256, 0, stream>>>(hbuf, rs, ssrc, agg);
        if (i < NLAYERS - 1) {
            float* gs = gstats + (i + 1) * 256;
            gemm_kernel<8, 8, true, false, false, true><<<GB, 256, 0, stream>>>(
                agg, hbuf, Wt_cat + i * 128 * 256, bl + i * 128, ybuf, HD, HD, gs);
            bn_apply_kernel<<<1600, 256, 0, stream>>>(ybuf, gs, g_bn + i * 128, b_bn + i * 128, hbuf);
        } else {
            gemm_kernel<8, 8, true, false, false, false><<<GB, 256, 0, stream>>>(
                agg, hbuf, Wt_cat + i * 128 * 256, bl + i * 128, ybuf, HD, HD, nullptr);
        }
    }

    // output layer: out = h4 @ W_out + b_out  (h4 lives in ybuf, no BN on last layer)
    gemm_kernel<3, 4, false, false, true, false><<<GB, 256, 0, stream>>>(
        ybuf, nullptr, Wt_out, b_out, out, COUT, COUT, nullptr);
}

// Round 7
// 650.997 us; speedup vs baseline: 2.6984x; 1.0157x over previous
//
#include <hip/hip_runtime.h>

#define N_NODES 100000
#define N_EDGES 1600000
#define HD 128
#define NLAYERS 4
#define COUT 40
#define BN_EPS 1e-5f
#define NBUCK 782                 // buckets of 128 nodes: (100000+127)/128
#define BUCK_CAP 3072             // mean 2048, sigma ~45 -> 22-sigma margin
constexpr int GB = (N_NODES + 127) / 128;   // 782 gemm blocks

typedef _Float16 half8 __attribute__((ext_vector_type(8)));
typedef float floatx4 __attribute__((ext_vector_type(4)));

// ---- weight transpose + fp32->fp16 prep: Wt[n][k] so B-fragments are contiguous ----
__global__ void prep_kernel(const float* __restrict__ W_in,
                            const float* __restrict__ Wl,
                            const float* __restrict__ Wr,
                            const float* __restrict__ W_out,
                            _Float16* __restrict__ Wt_in,    // [128][128]
                            _Float16* __restrict__ Wt_cat,   // [4][128][256] (k<128->Wl, k>=128->Wr)
                            _Float16* __restrict__ Wt_out)   // [48][128], rows(n) >= 40 zero
{
    int tid = blockIdx.x * blockDim.x + threadIdx.x;
    int stride = gridDim.x * blockDim.x;
    for (int idx = tid; idx < 128 * 128; idx += stride) {
        int n = idx >> 7, k = idx & 127;
        Wt_in[idx] = (_Float16)W_in[k * 128 + n];
    }
    for (int idx = tid; idx < 4 * 128 * 256; idx += stride) {
        int i = idx >> 15;
        int r = idx & 32767;
        int n = r >> 8, k = r & 255;
        Wt_cat[idx] = (_Float16)((k < 128) ? Wl[i * 16384 + k * 128 + n]
                                           : Wr[i * 16384 + (k - 128) * 128 + n]);
    }
    for (int idx = tid; idx < 48 * 128; idx += stride) {
        int n = idx >> 7, k = idx & 127;
        Wt_out[idx] = (n < COUT) ? (_Float16)W_out[k * COUT + n] : (_Float16)0.f;
    }
}

// ---- CSR build, phase 1: bucket histogram (LDS-staged, ~50K global atomics) ----
__global__ __launch_bounds__(256) void bucket_hist_kernel(const int* __restrict__ edst,
                                                          int* __restrict__ bcnt) {
    __shared__ int h[NBUCK];
    for (int b = threadIdx.x; b < NBUCK; b += 256) h[b] = 0;
    __syncthreads();
    int tid = blockIdx.x * 256 + threadIdx.x;
    int stride = gridDim.x * 256;
    for (int e = tid; e < N_EDGES; e += stride)
        atomicAdd(&h[edst[e] >> 7], 1);
    __syncthreads();
    for (int b = threadIdx.x; b < NBUCK; b += 256)
        if (h[b]) atomicAdd(&bcnt[b], h[b]);
}

// ---- phase 2: one-wave exclusive scan of bucket counts -> bbase, bcur ----
__global__ void bucket_scan_kernel(const int* __restrict__ bcnt,
                                   int* __restrict__ bbase, int* __restrict__ bcur) {
    int lane = threadIdx.x;
    int run = 0;
    for (int base = 0; base < NBUCK; base += 64) {
        int i = base + lane;
        int orig = (i < NBUCK) ? bcnt[i] : 0;
        int v = orig;
        #pragma unroll
        for (int off = 1; off < 64; off <<= 1) {
            int t = __shfl_up(v, off);
            if (lane >= off) v += t;
        }
        int total = __shfl(v, 63);
        int excl = v - orig + run;
        if (i < NBUCK) { bbase[i] = excl; bcur[i] = excl; }
        run += total;
    }
    if (lane == 0) bbase[NBUCK] = run;   // == N_EDGES
}

// ---- phase 3: bucketed scatter; rank via LDS atomics, 1 global atomic/bucket/tile ----
#define SCAT_T 16
__global__ __launch_bounds__(512) void bucket_scatter_kernel(const int* __restrict__ esrc,
                                                             const int* __restrict__ edst,
                                                             int* __restrict__ bcur,
                                                             int* __restrict__ bedges) {
    __shared__ int cnt[NBUCK], gpos[NBUCK];
    long base = (long)blockIdx.x * (512 * SCAT_T);
    for (int b = threadIdx.x; b < NBUCK; b += 512) cnt[b] = 0;
    __syncthreads();
    int srcs[SCAT_T], locs[SCAT_T], rnk[SCAT_T], bks[SCAT_T];
    #pragma unroll
    for (int j = 0; j < SCAT_T; ++j) {
        long e = base + j * 512 + threadIdx.x;
        if (e < N_EDGES) {
            int d = edst[e];
            srcs[j] = esrc[e];
            bks[j] = d >> 7;
            locs[j] = d & 127;
            rnk[j] = atomicAdd(&cnt[bks[j]], 1);
        } else bks[j] = -1;
    }
    __syncthreads();
    for (int b = threadIdx.x; b < NBUCK; b += 512) {
        int c = cnt[b];
        gpos[b] = c ? atomicAdd(&bcur[b], c) : 0;
    }
    __syncthreads();
    #pragma unroll
    for (int j = 0; j < SCAT_T; ++j)
        if (bks[j] >= 0)
            bedges[gpos[bks[j]] + rnk[j]] = (locs[j] << 17) | srcs[j];
}

// ---- phase 4: per-bucket LDS counting sort -> rs (coalesced) + ssrc ----
__global__ __launch_bounds__(256) void bucket_sort_kernel(const int* __restrict__ bedges,
                                                          const int* __restrict__ bbase,
                                                          int* __restrict__ rs,
                                                          int* __restrict__ ssrc) {
    __shared__ int lsrc[BUCK_CAP];
    __shared__ int h[128], hin[128], lcur[128];
    int b = blockIdx.x;
    int s = bbase[b];
    int n = bbase[b + 1] - s;
    if (n > BUCK_CAP) n = BUCK_CAP;   // statistically impossible; LDS safety
    if (threadIdx.x < 128) h[threadIdx.x] = 0;
    __syncthreads();
    for (int i = threadIdx.x; i < n; i += 256) {
        int v = bedges[s + i];
        lsrc[i] = v;
        atomicAdd(&h[v >> 17], 1);
    }
    __syncthreads();
    if (threadIdx.x < 128) hin[threadIdx.x] = h[threadIdx.x];
    __syncthreads();
    #pragma unroll
    for (int off = 1; off < 128; off <<= 1) {   // Hillis-Steele inclusive scan
        int t = 0;
        if (threadIdx.x < 128 && (int)threadIdx.x >= off) t = h[threadIdx.x - off];
        __syncthreads();
        if (threadIdx.x < 128) h[threadIdx.x] += t;
        __syncthreads();
    }
    if (threadIdx.x < 128) {
        int excl = h[threadIdx.x] - hin[threadIdx.x];
        lcur[threadIdx.x] = excl;
        int node = b * 128 + threadIdx.x;
        if (node < N_NODES) rs[node] = s + excl;
    }
    if (b == NBUCK - 1 && threadIdx.x == 0) rs[N_NODES] = bbase[NBUCK];
    __syncthreads();
    for (int i = threadIdx.x; i < n; i += 256) {
        int v = lsrc[i];
        int r = atomicAdd(&lcur[v >> 17], 1);
        ssrc[s + r] = v & 0x1FFFF;   // scattered only within this bucket's 12 KB
    }
}

// ---- mean aggregation v3: one dst per 16-lane group (4 dsts/wave) ----
// No cross-group reduce; packed fp16 accumulation (v_pk_add_f16), two
// pairwise accumulators to halve the rounding chain. Lane covers cols
// [l16*8, l16*8+8) via one 16B load per edge per group.
__global__ __launch_bounds__(256) void aggregate_kernel(const _Float16* __restrict__ H,
                                                        const int* __restrict__ rs,
                                                        const int* __restrict__ ssrc,
                                                        _Float16* __restrict__ AGG) {
    int wid = (blockIdx.x * 256 + threadIdx.x) >> 6;   // global wave id
    int lane = threadIdx.x & 63;
    int grp = lane >> 4, l16 = lane & 15;
    int dst = wid * 4 + grp;                           // exact: 25000 waves x 4
    int e0 = rs[dst], e1 = rs[dst + 1];
    int deg = e1 - e0;

    half8 acca = {0, 0, 0, 0, 0, 0, 0, 0};
    half8 accb = {0, 0, 0, 0, 0, 0, 0, 0};
    const _Float16* __restrict__ Hc = H + l16 * 8;

    int e = e0;
    for (; e + 4 <= e1; e += 4) {
        int s0 = ssrc[e], s1 = ssrc[e + 1], s2 = ssrc[e + 2], s3 = ssrc[e + 3];
        half8 v0 = *(const half8*)(Hc + (long)s0 * HD);
        half8 v1 = *(const half8*)(Hc + (long)s1 * HD);
        half8 v2 = *(const half8*)(Hc + (long)s2 * HD);
        half8 v3 = *(const half8*)(Hc + (long)s3 * HD);
        acca += v0 + v1;
        accb += v2 + v3;
    }
    for (; e < e1; ++e) {
        half8 v0 = *(const half8*)(Hc + (long)ssrc[e] * HD);
        acca += v0;
    }
    half8 acc = acca + accb;
    _Float16 inv = (_Float16)(1.f / (float)max(deg, 1));
    acc *= inv;
    *(half8*)(AGG + (long)dst * HD + l16 * 8) = acc;
}

// ---- MFMA GEMM: Y[r][c] = concat(A0,A1)[r][:] . Wt[c][:] + bias[c] ----
// B staged in LDS per block in fragment order [s][c][quad][l16][8]: each
// B-fragment is one conflict-free ds_read_b128 (consecutive lanes 16 B apart).
// K chunked x128 so LDS stays <= 32 KB. STATS: column sums/sq-sums in LDS
// (overlaid on B-buffer after compute), one global atomicAdd per column.
template <int CT, int KS, bool HAS_A1, bool A_F32, bool OUT_F32, bool STATS>
__global__ __launch_bounds__(256, 2) void gemm_kernel(const void* __restrict__ A0v,
                                                      const _Float16* __restrict__ A1,
                                                      const _Float16* __restrict__ Wt,
                                                      const float* __restrict__ bias,
                                                      void* __restrict__ Yv,
                                                      int out_stride, int ncols,
                                                      float* __restrict__ gstats) {
    constexpr int K = KS * 32;
    constexpr int KSC = (KS > 4) ? 4 : KS;              // K-chunk = KSC*32 <= 128
    __shared__ _Float16 bsm[KSC * 32 * CT * 16];        // <= 32 KB
    int wave = threadIdx.x >> 6;
    int lane = threadIdx.x & 63;
    int quad = lane >> 4;
    int l16 = lane & 15;
    int row_base = (blockIdx.x * 4 + wave) * 32;
    bool active = row_base < N_NODES;

    floatx4 acc[2][CT];
    #pragma unroll
    for (int rt = 0; rt < 2; ++rt)
        #pragma unroll
        for (int c = 0; c < CT; ++c)
            acc[rt][c] = (floatx4){0.f, 0.f, 0.f, 0.f};

    for (int ch = 0; ch < KS; ch += KSC) {
        if (ch) __syncthreads();   // previous chunk fully consumed
        for (int i = threadIdx.x; i < KSC * CT * 64; i += 256) {
            int n = i % (CT * 16);
            int ko = i / (CT * 16);                      // octet index in chunk
            half8 v = *(const half8*)(Wt + n * K + (ch * 4 + ko) * 8);
            int slot = (((ko >> 2) * CT + (n >> 4)) * 4 + (ko & 3)) * 16 + (n & 15);
            *(half8*)(bsm + slot * 8) = v;
        }
        __syncthreads();
        if (active) {
            #pragma unroll
            for (int s2 = 0; s2 < KSC; ++s2) {
                int s = ch + s2;
                int kk = s * 32 + quad * 8;
                half8 afrag[2];
                #pragma unroll
                for (int rt = 0; rt < 2; ++rt) {
                    int r = row_base + rt * 16 + l16;
                    if (r > N_NODES - 1) r = N_NODES - 1;  // clamp read, store guarded below
                    if (A_F32) {
                        const float* p = (const float*)A0v + (long)r * 128 + kk;
                        floatx4 f0 = *(const floatx4*)p;
                        floatx4 f1 = *(const floatx4*)(p + 4);
                        #pragma unroll
                        for (int j = 0; j < 4; ++j) {
                            afrag[rt][j]     = (_Float16)f0[j];
                            afrag[rt][4 + j] = (_Float16)f1[j];
                        }
                    } else {
                        const _Float16* p;
                        if (HAS_A1 && kk >= 128) p = A1 + (long)r * 128 + (kk - 128);
                        else                     p = (const _Float16*)A0v + (long)r * 128 + kk;
                        afrag[rt] = *(const half8*)p;
                    }
                }
                #pragma unroll
                for (int c = 0; c < CT; ++c) {
                    half8 bfrag = *(const half8*)(bsm + ((s2 * CT + c) * 64 + lane) * 8);
                    #pragma unroll
                    for (int rt = 0; rt < 2; ++rt)
                        acc[rt][c] = __builtin_amdgcn_mfma_f32_16x16x32_f16(afrag[rt], bfrag, acc[rt][c], 0, 0, 0);
                }
            }
        }
    }

    float* lsum = (float*)bsm;      // overlay stats on B-buffer (done with it)
    float* lsq  = lsum + 128;
    if (STATS) {
        __syncthreads();
        if (threadIdx.x < 128) { lsum[threadIdx.x] = 0.f; lsq[threadIdx.x] = 0.f; }
        __syncthreads();
    } else {
        if (!active) return;
    }

    #pragma unroll
    for (int c = 0; c < CT; ++c) {
        int col = c * 16 + l16;
        float s_c = 0.f, q_c = 0.f;
        if (active && col < ncols) {
            float bv = bias[col];
            #pragma unroll
            for (int rt = 0; rt < 2; ++rt) {
                #pragma unroll
                for (int i = 0; i < 4; ++i) {
                    int r = row_base + rt * 16 + quad * 4 + i;
                    if (r < N_NODES) {
                        float v = acc[rt][c][i] + bv;
                        if (OUT_F32) ((float*)Yv)[(long)r * out_stride + col] = v;
                        else         ((_Float16*)Yv)[(long)r * out_stride + col] = (_Float16)v;
                        if (STATS) { s_c += v; q_c += v * v; }
                    }
                }
            }
        }
        if (STATS) {
            s_c += __shfl_xor(s_c, 16); s_c += __shfl_xor(s_c, 32);
            q_c += __shfl_xor(q_c, 16); q_c += __shfl_xor(q_c, 32);
            if (lane < 16 && active) {
                atomicAdd(&lsum[col], s_c);
                atomicAdd(&lsq[col], q_c);
            }
        }
    }

    if (STATS) {
        __syncthreads();
        if (threadIdx.x < 128) {
            atomicAdd(&gstats[threadIdx.x], lsum[threadIdx.x]);
            atomicAdd(&gstats[128 + threadIdx.x], lsq[threadIdx.x]);
        }
    }
}

// ---- BN apply: each block derives scale/shift from gstats (redundant, trivial) ----
__global__ __launch_bounds__(256) void bn_apply_kernel(const _Float16* __restrict__ Y,
                                                       const float* __restrict__ gstats,
                                                       const float* __restrict__ g,
                                                       const float* __restrict__ b,
                                                       _Float16* __restrict__ H) {
    __shared__ float sc[128], sh[128];
    if (threadIdx.x < 128) {
        int col = threadIdx.x;
        float m = gstats[col] * (1.f / (float)N_NODES);
        float v = gstats[128 + col] * (1.f / (float)N_NODES) - m * m;
        float s = g[col] * rsqrtf(v + BN_EPS);
        sc[col] = s;
        sh[col] = b[col] - m * s;
    }
    __syncthreads();
    long total = (long)N_NODES * HD / 8;
    for (long t = (long)blockIdx.x * blockDim.x + threadIdx.x; t < total;
         t += (long)gridDim.x * blockDim.x) {
        long base = t * 8;
        int col0 = (int)(base & 127);
        half8 in = *(const half8*)(Y + base);
        half8 outv;
        #pragma unroll
        for (int j = 0; j < 8; ++j) {
            float v = (float)in[j];
            float r = v * sc[col0 + j] + sh[col0 + j];
            outv[j] = (_Float16)fmaxf(r, 0.f);
        }
        *(half8*)(H + base) = outv;
    }
}

extern "C" void kernel_launch(void* const* d_in, const int* in_sizes, int n_in,
                              void* d_out, int out_size, void* d_ws, size_t ws_size,
                              hipStream_t stream) {
    (void)in_sizes; (void)n_in; (void)out_size; (void)ws_size;
    const float* x       = (const float*)d_in[0];
    const float* W_in    = (const float*)d_in[1];
    const float* b_in    = (const float*)d_in[2];
    const float* g_in    = (const float*)d_in[3];
    const float* beta_in = (const float*)d_in[4];
    const float* Wl      = (const float*)d_in[5];
    const float* bl      = (const float*)d_in[6];
    const float* Wr      = (const float*)d_in[7];
    const float* g_bn    = (const float*)d_in[8];
    const float* b_bn    = (const float*)d_in[9];
    const float* W_out   = (const float*)d_in[10];
    const float* b_out   = (const float*)d_in[11];
    const int*   ei      = (const int*)d_in[12];
    const int* esrc = ei;
    const int* edst = ei + N_EDGES;
    float* out = (float*)d_out;

    char* w = (char*)d_ws;
    auto alloc = [&](size_t bytes) -> char* {
        char* p = w; w += (bytes + 255) & ~(size_t)255; return p;
    };
    int* rs           = (int*)alloc((N_NODES + 1) * sizeof(int));
    int* bcnt         = (int*)alloc((NBUCK + 1) * sizeof(int));
    int* bbase        = (int*)alloc((NBUCK + 1) * sizeof(int));
    int* bcur         = (int*)alloc(NBUCK * sizeof(int));
    int* ssrc         = (int*)alloc(N_EDGES * sizeof(int));
    _Float16* Wt_in   = (_Float16*)alloc(128 * 128 * 2);
    _Float16* Wt_cat  = (_Float16*)alloc(4 * 128 * 256 * 2);
    _Float16* Wt_out  = (_Float16*)alloc(48 * 128 * 2);
    _Float16* hbuf    = (_Float16*)alloc((size_t)N_NODES * HD * 2);
    _Float16* agg     = (_Float16*)alloc((size_t)N_NODES * HD * 2);
    _Float16* ybuf    = (_Float16*)alloc((size_t)N_NODES * HD * 2);
    float* gstats     = (float*)alloc(4 * 256 * 4);   // [layer][sum128|sq128]
    int* bedges       = (int*)agg;   // alias: dead before first aggregate

    hipMemsetAsync(bcnt, 0, (NBUCK + 1) * sizeof(int), stream);
    hipMemsetAsync(gstats, 0, 4 * 256 * 4, stream);
    prep_kernel<<<256, 256, 0, stream>>>(W_in, Wl, Wr, W_out, Wt_in, Wt_cat, Wt_out);
    bucket_hist_kernel<<<64, 256, 0, stream>>>(edst, bcnt);
    bucket_scan_kernel<<<1, 64, 0, stream>>>(bcnt, bbase, bcur);
    bucket_scatter_kernel<<<(N_EDGES + 8191) / 8192, 512, 0, stream>>>(esrc, edst, bcur, bedges);
    bucket_sort_kernel<<<NBUCK, 256, 0, stream>>>(bedges, bbase, rs, ssrc);

    // input layer: y = x @ W_in + b_in ; h = relu(bn(y))  (stats fused in gemm)
    gemm_kernel<8, 4, false, true, false, true><<<GB, 256, 0, stream>>>(
        x, nullptr, Wt_in, b_in, ybuf, HD, HD, gstats);
    bn_apply_kernel<<<1600, 256, 0, stream>>>(ybuf, gstats, g_in, beta_in, hbuf);

    for (int i = 0; i < NLAYERS; ++i) {
        aggregate_kernel<<<N_NODES / 16, 256, 0, stream>>>(hbuf, rs, ssrc, agg);
        if (i < NLAYERS - 1) {
            float* gs = gstats + (i + 1) * 256;
            gemm_kernel<8, 8, true, false, false, true><<<GB, 256, 0, stream>>>(
                agg, hbuf, Wt_cat + i * 128 * 256, bl + i * 128, ybuf, HD, HD, gs);
            bn_apply_kernel<<<1600, 256, 0, stream>>>(ybuf, gs, g_bn + i * 128, b_bn + i * 128, hbuf);
        } else {
            gemm_kernel<8, 8, true, false, false, false><<<GB, 256, 0, stream>>>(
                agg, hbuf, Wt_cat + i * 128 * 256, bl + i * 128, ybuf, HD, HD, nullptr);
        }
    }

    // output layer: out = h4 @ W_out + b_out  (h4 lives in ybuf, no BN on last layer)
    gemm_kernel<3, 4, false, false, true, false><<<GB, 256, 0, stream>>>(
        ybuf, nullptr, Wt_out, b_out, out, COUT, COUT, nullptr);
}

// Round 8
// 625.863 us; speedup vs baseline: 2.8068x; 1.0402x over previous
//
#include <hip/hip_runtime.h>

#define N_NODES 100000
#define N_EDGES 1600000
#define HD 128
#define NLAYERS 4
#define COUT 40
#define BN_EPS 1e-5f
#define NBUCK 782                 // buckets of 128 nodes: (100000+127)/128
#define BUCK_CAP 3072             // mean 2048, sigma ~45 -> 22-sigma margin
constexpr int GB = (N_NODES + 127) / 128;   // 782 gemm blocks

typedef _Float16 half8 __attribute__((ext_vector_type(8)));
typedef float floatx4 __attribute__((ext_vector_type(4)));

__device__ __forceinline__ half8 bnrelu8(half8 v, half8 s, half8 h) {
    half8 t = s * v + h;
    half8 z = {0, 0, 0, 0, 0, 0, 0, 0};
    return __builtin_elementwise_max(t, z);
}

// ---- weight transpose + fp32->fp16 prep: Wt[n][k] so B-fragments are contiguous ----
__global__ void prep_kernel(const float* __restrict__ W_in,
                            const float* __restrict__ Wl,
                            const float* __restrict__ Wr,
                            const float* __restrict__ W_out,
                            _Float16* __restrict__ Wt_in,    // [128][128]
                            _Float16* __restrict__ Wt_cat,   // [4][128][256] (k<128->Wl, k>=128->Wr)
                            _Float16* __restrict__ Wt_out)   // [48][128], rows(n) >= 40 zero
{
    int tid = blockIdx.x * blockDim.x + threadIdx.x;
    int stride = gridDim.x * blockDim.x;
    for (int idx = tid; idx < 128 * 128; idx += stride) {
        int n = idx >> 7, k = idx & 127;
        Wt_in[idx] = (_Float16)W_in[k * 128 + n];
    }
    for (int idx = tid; idx < 4 * 128 * 256; idx += stride) {
        int i = idx >> 15;
        int r = idx & 32767;
        int n = r >> 8, k = r & 255;
        Wt_cat[idx] = (_Float16)((k < 128) ? Wl[i * 16384 + k * 128 + n]
                                           : Wr[i * 16384 + (k - 128) * 128 + n]);
    }
    for (int idx = tid; idx < 48 * 128; idx += stride) {
        int n = idx >> 7, k = idx & 127;
        Wt_out[idx] = (n < COUT) ? (_Float16)W_out[k * COUT + n] : (_Float16)0.f;
    }
}

// ---- CSR build, phase 1: bucket histogram (LDS-staged, ~50K global atomics) ----
__global__ __launch_bounds__(256) void bucket_hist_kernel(const int* __restrict__ edst,
                                                          int* __restrict__ bcnt) {
    __shared__ int h[NBUCK];
    for (int b = threadIdx.x; b < NBUCK; b += 256) h[b] = 0;
    __syncthreads();
    int tid = blockIdx.x * 256 + threadIdx.x;
    int stride = gridDim.x * 256;
    for (int e = tid; e < N_EDGES; e += stride)
        atomicAdd(&h[edst[e] >> 7], 1);
    __syncthreads();
    for (int b = threadIdx.x; b < NBUCK; b += 256)
        if (h[b]) atomicAdd(&bcnt[b], h[b]);
}

// ---- phase 2: one-wave exclusive scan of bucket counts -> bbase, bcur ----
__global__ void bucket_scan_kernel(const int* __restrict__ bcnt,
                                   int* __restrict__ bbase, int* __restrict__ bcur) {
    int lane = threadIdx.x;
    int run = 0;
    for (int base = 0; base < NBUCK; base += 64) {
        int i = base + lane;
        int orig = (i < NBUCK) ? bcnt[i] : 0;
        int v = orig;
        #pragma unroll
        for (int off = 1; off < 64; off <<= 1) {
            int t = __shfl_up(v, off);
            if (lane >= off) v += t;
        }
        int total = __shfl(v, 63);
        int excl = v - orig + run;
        if (i < NBUCK) { bbase[i] = excl; bcur[i] = excl; }
        run += total;
    }
    if (lane == 0) bbase[NBUCK] = run;   // == N_EDGES
}

// ---- phase 3: bucketed scatter; rank via LDS atomics, 1 global atomic/bucket/tile ----
#define SCAT_T 16
__global__ __launch_bounds__(512) void bucket_scatter_kernel(const int* __restrict__ esrc,
                                                             const int* __restrict__ edst,
                                                             int* __restrict__ bcur,
                                                             int* __restrict__ bedges) {
    __shared__ int cnt[NBUCK], gpos[NBUCK];
    long base = (long)blockIdx.x * (512 * SCAT_T);
    for (int b = threadIdx.x; b < NBUCK; b += 512) cnt[b] = 0;
    __syncthreads();
    int srcs[SCAT_T], locs[SCAT_T], rnk[SCAT_T], bks[SCAT_T];
    #pragma unroll
    for (int j = 0; j < SCAT_T; ++j) {
        long e = base + j * 512 + threadIdx.x;
        if (e < N_EDGES) {
            int d = edst[e];
            srcs[j] = esrc[e];
            bks[j] = d >> 7;
            locs[j] = d & 127;
            rnk[j] = atomicAdd(&cnt[bks[j]], 1);
        } else bks[j] = -1;
    }
    __syncthreads();
    for (int b = threadIdx.x; b < NBUCK; b += 512) {
        int c = cnt[b];
        gpos[b] = c ? atomicAdd(&bcur[b], c) : 0;
    }
    __syncthreads();
    #pragma unroll
    for (int j = 0; j < SCAT_T; ++j)
        if (bks[j] >= 0)
            bedges[gpos[bks[j]] + rnk[j]] = (locs[j] << 17) | srcs[j];
}

// ---- phase 4: per-bucket LDS counting sort -> rs (coalesced) + ssrc ----
__global__ __launch_bounds__(256) void bucket_sort_kernel(const int* __restrict__ bedges,
                                                          const int* __restrict__ bbase,
                                                          int* __restrict__ rs,
                                                          int* __restrict__ ssrc) {
    __shared__ int lsrc[BUCK_CAP];
    __shared__ int h[128], hin[128], lcur[128];
    int b = blockIdx.x;
    int s = bbase[b];
    int n = bbase[b + 1] - s;
    if (n > BUCK_CAP) n = BUCK_CAP;   // statistically impossible; LDS safety
    if (threadIdx.x < 128) h[threadIdx.x] = 0;
    __syncthreads();
    for (int i = threadIdx.x; i < n; i += 256) {
        int v = bedges[s + i];
        lsrc[i] = v;
        atomicAdd(&h[v >> 17], 1);
    }
    __syncthreads();
    if (threadIdx.x < 128) hin[threadIdx.x] = h[threadIdx.x];
    __syncthreads();
    #pragma unroll
    for (int off = 1; off < 128; off <<= 1) {   // Hillis-Steele inclusive scan
        int t = 0;
        if (threadIdx.x < 128 && (int)threadIdx.x >= off) t = h[threadIdx.x - off];
        __syncthreads();
        if (threadIdx.x < 128) h[threadIdx.x] += t;
        __syncthreads();
    }
    if (threadIdx.x < 128) {
        int excl = h[threadIdx.x] - hin[threadIdx.x];
        lcur[threadIdx.x] = excl;
        int node = b * 128 + threadIdx.x;
        if (node < N_NODES) rs[node] = s + excl;
    }
    if (b == NBUCK - 1 && threadIdx.x == 0) rs[N_NODES] = bbase[NBUCK];
    __syncthreads();
    for (int i = threadIdx.x; i < n; i += 256) {
        int v = lsrc[i];
        int r = atomicAdd(&lcur[v >> 17], 1);
        ssrc[s + r] = v & 0x1FFFF;   // scattered only within this bucket's 12 KB
    }
}

// ---- mean aggregation v4: one dst per 16-lane group, BN+ReLU applied on the fly ----
// Reads pre-BN Y; h = relu(sc*y+sh) computed per gathered row (pk fp16) from a
// 512 B LDS scale/shift table derived from gstats. No bn_apply kernel needed.
__global__ __launch_bounds__(256) void aggregate_kernel(const _Float16* __restrict__ Y,
                                                        const int* __restrict__ rs,
                                                        const int* __restrict__ ssrc,
                                                        const float* __restrict__ gstats,
                                                        const float* __restrict__ g,
                                                        const float* __restrict__ b,
                                                        _Float16* __restrict__ AGG) {
    __shared__ _Float16 sc16[128], sh16[128];
    if (threadIdx.x < 128) {
        int col = threadIdx.x;
        float m = gstats[col] * (1.f / (float)N_NODES);
        float v = gstats[128 + col] * (1.f / (float)N_NODES) - m * m;
        float s = g[col] * rsqrtf(v + BN_EPS);
        sc16[col] = (_Float16)s;
        sh16[col] = (_Float16)(b[col] - m * s);
    }
    __syncthreads();

    int wid = (blockIdx.x * 256 + threadIdx.x) >> 6;   // global wave id
    int lane = threadIdx.x & 63;
    int grp = lane >> 4, l16 = lane & 15;
    int dst = wid * 4 + grp;                           // exact: 25000 waves x 4
    int e0 = rs[dst], e1 = rs[dst + 1];
    int deg = e1 - e0;

    half8 scv = *(const half8*)(sc16 + l16 * 8);
    half8 shv = *(const half8*)(sh16 + l16 * 8);
    half8 acca = {0, 0, 0, 0, 0, 0, 0, 0};
    half8 accb = {0, 0, 0, 0, 0, 0, 0, 0};
    const _Float16* __restrict__ Yc = Y + l16 * 8;

    int e = e0;
    for (; e + 4 <= e1; e += 4) {
        int s0 = ssrc[e], s1 = ssrc[e + 1], s2 = ssrc[e + 2], s3 = ssrc[e + 3];
        half8 v0 = *(const half8*)(Yc + (long)s0 * HD);
        half8 v1 = *(const half8*)(Yc + (long)s1 * HD);
        half8 v2 = *(const half8*)(Yc + (long)s2 * HD);
        half8 v3 = *(const half8*)(Yc + (long)s3 * HD);
        acca += bnrelu8(v0, scv, shv) + bnrelu8(v1, scv, shv);
        accb += bnrelu8(v2, scv, shv) + bnrelu8(v3, scv, shv);
    }
    for (; e < e1; ++e) {
        half8 v0 = *(const half8*)(Yc + (long)ssrc[e] * HD);
        acca += bnrelu8(v0, scv, shv);
    }
    half8 acc = acca + accb;
    _Float16 inv = (_Float16)(1.f / (float)max(deg, 1));
    acc *= inv;
    *(half8*)(AGG + (long)dst * HD + l16 * 8) = acc;
}

// ---- MFMA GEMM: Y[r][c] = concat(A0, bnrelu(A1))[r][:] . Wt[c][:] + bias[c] ----
// B staged in LDS in fragment order (conflict-free ds_read_b128). BN_A1: the
// root-path fragments (k >= 128) get relu(sc*v+sh) applied from an LDS table.
// STATS: column sums/sq-sums -> one global atomicAdd per column into gstats_out.
template <int CT, int KS, bool HAS_A1, bool A_F32, bool OUT_F32, bool STATS, bool BN_A1>
__global__ __launch_bounds__(256, 2) void gemm_kernel(const void* __restrict__ A0v,
                                                      const _Float16* __restrict__ A1,
                                                      const _Float16* __restrict__ Wt,
                                                      const float* __restrict__ bias,
                                                      void* __restrict__ Yv,
                                                      int out_stride, int ncols,
                                                      float* __restrict__ gstats_out,
                                                      const float* __restrict__ bn_stats,
                                                      const float* __restrict__ bn_g,
                                                      const float* __restrict__ bn_b) {
    constexpr int K = KS * 32;
    constexpr int KSC = (KS > 4) ? 4 : KS;              // K-chunk = KSC*32 <= 128
    __shared__ _Float16 bsm[KSC * 32 * CT * 16];        // <= 32 KB
    __shared__ _Float16 a1sc[128], a1sh[128];
    int wave = threadIdx.x >> 6;
    int lane = threadIdx.x & 63;
    int quad = lane >> 4;
    int l16 = lane & 15;
    int row_base = (blockIdx.x * 4 + wave) * 32;
    bool active = row_base < N_NODES;

    if (BN_A1) {
        if (threadIdx.x < 128) {
            int col = threadIdx.x;
            float m = bn_stats[col] * (1.f / (float)N_NODES);
            float v = bn_stats[128 + col] * (1.f / (float)N_NODES) - m * m;
            float s = bn_g[col] * rsqrtf(v + BN_EPS);
            a1sc[col] = (_Float16)s;
            a1sh[col] = (_Float16)(bn_b[col] - m * s);
        }
        // covered by the staging __syncthreads below
    }

    floatx4 acc[2][CT];
    #pragma unroll
    for (int rt = 0; rt < 2; ++rt)
        #pragma unroll
        for (int c = 0; c < CT; ++c)
            acc[rt][c] = (floatx4){0.f, 0.f, 0.f, 0.f};

    for (int ch = 0; ch < KS; ch += KSC) {
        if (ch) __syncthreads();   // previous chunk fully consumed
        for (int i = threadIdx.x; i < KSC * CT * 64; i += 256) {
            int n = i % (CT * 16);
            int ko = i / (CT * 16);                      // octet index in chunk
            half8 v = *(const half8*)(Wt + n * K + (ch * 4 + ko) * 8);
            int slot = (((ko >> 2) * CT + (n >> 4)) * 4 + (ko & 3)) * 16 + (n & 15);
            *(half8*)(bsm + slot * 8) = v;
        }
        __syncthreads();
        if (active) {
            #pragma unroll
            for (int s2 = 0; s2 < KSC; ++s2) {
                int s = ch + s2;
                int kk = s * 32 + quad * 8;
                bool fromA1 = HAS_A1 && (kk >= 128);
                half8 afrag[2];
                #pragma unroll
                for (int rt = 0; rt < 2; ++rt) {
                    int r = row_base + rt * 16 + l16;
                    if (r > N_NODES - 1) r = N_NODES - 1;  // clamp read, store guarded below
                    if (A_F32) {
                        const float* p = (const float*)A0v + (long)r * 128 + kk;
                        floatx4 f0 = *(const floatx4*)p;
                        floatx4 f1 = *(const floatx4*)(p + 4);
                        #pragma unroll
                        for (int j = 0; j < 4; ++j) {
                            afrag[rt][j]     = (_Float16)f0[j];
                            afrag[rt][4 + j] = (_Float16)f1[j];
                        }
                    } else {
                        const _Float16* p;
                        if (fromA1) p = A1 + (long)r * 128 + (kk - 128);
                        else        p = (const _Float16*)A0v + (long)r * 128 + kk;
                        afrag[rt] = *(const half8*)p;
                        if (BN_A1 && fromA1) {
                            half8 s8 = *(const half8*)(a1sc + (kk - 128));
                            half8 h8 = *(const half8*)(a1sh + (kk - 128));
                            afrag[rt] = bnrelu8(afrag[rt], s8, h8);
                        }
                    }
                }
                #pragma unroll
                for (int c = 0; c < CT; ++c) {
                    half8 bfrag = *(const half8*)(bsm + ((s2 * CT + c) * 64 + lane) * 8);
                    #pragma unroll
                    for (int rt = 0; rt < 2; ++rt)
                        acc[rt][c] = __builtin_amdgcn_mfma_f32_16x16x32_f16(afrag[rt], bfrag, acc[rt][c], 0, 0, 0);
                }
            }
        }
    }

    float* lsum = (float*)bsm;      // overlay stats on B-buffer (done with it)
    float* lsq  = lsum + 128;
    if (STATS) {
        __syncthreads();
        if (threadIdx.x < 128) { lsum[threadIdx.x] = 0.f; lsq[threadIdx.x] = 0.f; }
        __syncthreads();
    } else {
        if (!active) return;
    }

    #pragma unroll
    for (int c = 0; c < CT; ++c) {
        int col = c * 16 + l16;
        float s_c = 0.f, q_c = 0.f;
        if (active && col < ncols) {
            float bv = bias[col];
            #pragma unroll
            for (int rt = 0; rt < 2; ++rt) {
                #pragma unroll
                for (int i = 0; i < 4; ++i) {
                    int r = row_base + rt * 16 + quad * 4 + i;
                    if (r < N_NODES) {
                        float v = acc[rt][c][i] + bv;
                        if (OUT_F32) ((float*)Yv)[(long)r * out_stride + col] = v;
                        else         ((_Float16*)Yv)[(long)r * out_stride + col] = (_Float16)v;
                        if (STATS) { s_c += v; q_c += v * v; }
                    }
                }
            }
        }
        if (STATS) {
            s_c += __shfl_xor(s_c, 16); s_c += __shfl_xor(s_c, 32);
            q_c += __shfl_xor(q_c, 16); q_c += __shfl_xor(q_c, 32);
            if (lane < 16 && active) {
                atomicAdd(&lsum[col], s_c);
                atomicAdd(&lsq[col], q_c);
            }
        }
    }

    if (STATS) {
        __syncthreads();
        if (threadIdx.x < 128) {
            atomicAdd(&gstats_out[threadIdx.x], lsum[threadIdx.x]);
            atomicAdd(&gstats_out[128 + threadIdx.x], lsq[threadIdx.x]);
        }
    }
}

extern "C" void kernel_launch(void* const* d_in, const int* in_sizes, int n_in,
                              void* d_out, int out_size, void* d_ws, size_t ws_size,
                              hipStream_t stream) {
    (void)in_sizes; (void)n_in; (void)out_size; (void)ws_size;
    const float* x       = (const float*)d_in[0];
    const float* W_in    = (const float*)d_in[1];
    const float* b_in    = (const float*)d_in[2];
    const float* g_in    = (const float*)d_in[3];
    const float* beta_in = (const float*)d_in[4];
    const float* Wl      = (const float*)d_in[5];
    const float* bl      = (const float*)d_in[6];
    const float* Wr      = (const float*)d_in[7];
    const float* g_bn    = (const float*)d_in[8];
    const float* b_bn    = (const float*)d_in[9];
    const float* W_out   = (const float*)d_in[10];
    const float* b_out   = (const float*)d_in[11];
    const int*   ei      = (const int*)d_in[12];
    const int* esrc = ei;
    const int* edst = ei + N_EDGES;
    float* out = (float*)d_out;

    char* w = (char*)d_ws;
    auto alloc = [&](size_t bytes) -> char* {
        char* p = w; w += (bytes + 255) & ~(size_t)255; return p;
    };
    int* rs           = (int*)alloc((N_NODES + 1) * sizeof(int));
    int* bcnt         = (int*)alloc((NBUCK + 1) * sizeof(int));
    int* bbase        = (int*)alloc((NBUCK + 1) * sizeof(int));
    int* bcur         = (int*)alloc(NBUCK * sizeof(int));
    int* ssrc         = (int*)alloc(N_EDGES * sizeof(int));
    _Float16* Wt_in   = (_Float16*)alloc(128 * 128 * 2);
    _Float16* Wt_cat  = (_Float16*)alloc(4 * 128 * 256 * 2);
    _Float16* Wt_out  = (_Float16*)alloc(48 * 128 * 2);
    _Float16* ybufA   = (_Float16*)alloc((size_t)N_NODES * HD * 2);
    _Float16* ybufB   = (_Float16*)alloc((size_t)N_NODES * HD * 2);
    _Float16* agg     = (_Float16*)alloc((size_t)N_NODES * HD * 2);
    float* gstats     = (float*)alloc(4 * 256 * 4);   // [layer][sum128|sq128]
    int* bedges       = (int*)agg;   // alias: dead before first aggregate

    hipMemsetAsync(bcnt, 0, (NBUCK + 1) * sizeof(int), stream);
    hipMemsetAsync(gstats, 0, 4 * 256 * 4, stream);
    prep_kernel<<<256, 256, 0, stream>>>(W_in, Wl, Wr, W_out, Wt_in, Wt_cat, Wt_out);
    bucket_hist_kernel<<<64, 256, 0, stream>>>(edst, bcnt);
    bucket_scan_kernel<<<1, 64, 0, stream>>>(bcnt, bbase, bcur);
    bucket_scatter_kernel<<<(N_EDGES + 8191) / 8192, 512, 0, stream>>>(esrc, edst, bcur, bedges);
    bucket_sort_kernel<<<NBUCK, 256, 0, stream>>>(bedges, bbase, rs, ssrc);

    // input layer: y0 = x @ W_in + b_in (stats -> gstats[0]); BN deferred to consumers
    gemm_kernel<8, 4, false, true, false, true, false><<<GB, 256, 0, stream>>>(
        x, nullptr, Wt_in, b_in, ybufA, HD, HD, gstats, nullptr, nullptr, nullptr);

    _Float16* cur = ybufA;
    _Float16* nxt = ybufB;
    for (int i = 0; i < NLAYERS; ++i) {
        const float* gs   = gstats + i * 256;
        const float* bn_g = (i == 0) ? g_in    : g_bn + (i - 1) * 128;
        const float* bn_b = (i == 0) ? beta_in : b_bn + (i - 1) * 128;
        aggregate_kernel<<<N_NODES / 16, 256, 0, stream>>>(cur, rs, ssrc, gs, bn_g, bn_b, agg);
        if (i < NLAYERS - 1) {
            gemm_kernel<8, 8, true, false, false, true, true><<<GB, 256, 0, stream>>>(
                agg, cur, Wt_cat + i * 128 * 256, bl + i * 128, nxt, HD, HD,
                gstats + (i + 1) * 256, gs, bn_g, bn_b);
        } else {
            gemm_kernel<8, 8, true, false, false, false, true><<<GB, 256, 0, stream>>>(
                agg, cur, Wt_cat + i * 128 * 256, bl + i * 128, nxt, HD, HD,
                nullptr, gs, bn_g, bn_b);
        }
        _Float16* t = cur; cur = nxt; nxt = t;
    }

    // output layer: out = y4 @ W_out + b_out  (y4 == cur, no BN on last layer)
    gemm_kernel<3, 4, false, false, true, false, false><<<GB, 256, 0, stream>>>(
        cur, nullptr, Wt_out, b_out, out, COUT, COUT, nullptr, nullptr, nullptr, nullptr);
}

// Round 9
// 614.175 us; speedup vs baseline: 2.8602x; 1.0190x over previous
//
#include <hip/hip_runtime.h>

#define N_NODES 100000
#define N_EDGES 1600000
#define HD 128
#define NLAYERS 4
#define COUT 40
#define BN_EPS 1e-5f
#define NBUCK 782                 // buckets of 128 nodes: (100000+127)/128
#define BUCK_CAP 3072             // mean 2048, sigma ~45 -> 22-sigma margin
constexpr int GB = (N_NODES + 127) / 128;   // 782 gemm blocks

typedef _Float16 half8 __attribute__((ext_vector_type(8)));
typedef float floatx4 __attribute__((ext_vector_type(4)));

__device__ __forceinline__ half8 bnrelu8(half8 v, half8 s, half8 h) {
    half8 t = s * v + h;
    half8 z = {0, 0, 0, 0, 0, 0, 0, 0};
    return __builtin_elementwise_max(t, z);
}

// ---- weight transpose + fp32->fp16 prep: Wt[n][k] so B-fragments are contiguous ----
__global__ void prep_kernel(const float* __restrict__ W_in,
                            const float* __restrict__ Wl,
                            const float* __restrict__ Wr,
                            const float* __restrict__ W_out,
                            _Float16* __restrict__ Wt_in,    // [128][128]
                            _Float16* __restrict__ Wt_cat,   // [4][128][256] (k<128->Wl, k>=128->Wr)
                            _Float16* __restrict__ Wt_out)   // [48][128], rows(n) >= 40 zero
{
    int tid = blockIdx.x * blockDim.x + threadIdx.x;
    int stride = gridDim.x * blockDim.x;
    for (int idx = tid; idx < 128 * 128; idx += stride) {
        int n = idx >> 7, k = idx & 127;
        Wt_in[idx] = (_Float16)W_in[k * 128 + n];
    }
    for (int idx = tid; idx < 4 * 128 * 256; idx += stride) {
        int i = idx >> 15;
        int r = idx & 32767;
        int n = r >> 8, k = r & 255;
        Wt_cat[idx] = (_Float16)((k < 128) ? Wl[i * 16384 + k * 128 + n]
                                           : Wr[i * 16384 + (k - 128) * 128 + n]);
    }
    for (int idx = tid; idx < 48 * 128; idx += stride) {
        int n = idx >> 7, k = idx & 127;
        Wt_out[idx] = (n < COUT) ? (_Float16)W_out[k * COUT + n] : (_Float16)0.f;
    }
}

// ---- CSR build, phase 1: bucket histogram (LDS-staged) ----
__global__ __launch_bounds__(256) void bucket_hist_kernel(const int* __restrict__ edst,
                                                          int* __restrict__ bcnt) {
    __shared__ int h[NBUCK];
    for (int b = threadIdx.x; b < NBUCK; b += 256) h[b] = 0;
    __syncthreads();
    int tid = blockIdx.x * 256 + threadIdx.x;
    int stride = gridDim.x * 256;
    for (int e = tid; e < N_EDGES; e += stride)
        atomicAdd(&h[edst[e] >> 7], 1);
    __syncthreads();
    for (int b = threadIdx.x; b < NBUCK; b += 256)
        if (h[b]) atomicAdd(&bcnt[b], h[b]);
}

// ---- phase 2: one-wave exclusive scan of bucket counts -> bbase, bcur ----
__global__ void bucket_scan_kernel(const int* __restrict__ bcnt,
                                   int* __restrict__ bbase, int* __restrict__ bcur) {
    int lane = threadIdx.x;
    int run = 0;
    for (int base = 0; base < NBUCK; base += 64) {
        int i = base + lane;
        int orig = (i < NBUCK) ? bcnt[i] : 0;
        int v = orig;
        #pragma unroll
        for (int off = 1; off < 64; off <<= 1) {
            int t = __shfl_up(v, off);
            if (lane >= off) v += t;
        }
        int total = __shfl(v, 63);
        int excl = v - orig + run;
        if (i < NBUCK) { bbase[i] = excl; bcur[i] = excl; }
        run += total;
    }
    if (lane == 0) bbase[NBUCK] = run;   // == N_EDGES
}

// ---- phase 3: bucketed scatter; rank via LDS atomics, 1 global atomic/bucket/tile ----
#define SCAT_T 8
__global__ __launch_bounds__(512) void bucket_scatter_kernel(const int* __restrict__ esrc,
                                                             const int* __restrict__ edst,
                                                             int* __restrict__ bcur,
                                                             int* __restrict__ bedges) {
    __shared__ int cnt[NBUCK], gpos[NBUCK];
    long base = (long)blockIdx.x * (512 * SCAT_T);
    for (int b = threadIdx.x; b < NBUCK; b += 512) cnt[b] = 0;
    __syncthreads();
    int srcs[SCAT_T], locs[SCAT_T], rnk[SCAT_T], bks[SCAT_T];
    #pragma unroll
    for (int j = 0; j < SCAT_T; ++j) {
        long e = base + j * 512 + threadIdx.x;
        if (e < N_EDGES) {
            int d = edst[e];
            srcs[j] = esrc[e];
            bks[j] = d >> 7;
            locs[j] = d & 127;
            rnk[j] = atomicAdd(&cnt[bks[j]], 1);
        } else bks[j] = -1;
    }
    __syncthreads();
    for (int b = threadIdx.x; b < NBUCK; b += 512) {
        int c = cnt[b];
        gpos[b] = c ? atomicAdd(&bcur[b], c) : 0;
    }
    __syncthreads();
    #pragma unroll
    for (int j = 0; j < SCAT_T; ++j)
        if (bks[j] >= 0)
            bedges[gpos[bks[j]] + rnk[j]] = (locs[j] << 17) | srcs[j];
}

// ---- phase 4: per-bucket LDS counting sort -> rs (coalesced) + ssrc ----
__global__ __launch_bounds__(256) void bucket_sort_kernel(const int* __restrict__ bedges,
                                                          const int* __restrict__ bbase,
                                                          int* __restrict__ rs,
                                                          int* __restrict__ ssrc) {
    __shared__ int lsrc[BUCK_CAP];
    __shared__ int h[128], hin[128], lcur[128];
    int b = blockIdx.x;
    int s = bbase[b];
    int n = bbase[b + 1] - s;
    if (n > BUCK_CAP) n = BUCK_CAP;   // statistically impossible; LDS safety
    if (threadIdx.x < 128) h[threadIdx.x] = 0;
    __syncthreads();
    for (int i = threadIdx.x; i < n; i += 256) {
        int v = bedges[s + i];
        lsrc[i] = v;
        atomicAdd(&h[v >> 17], 1);
    }
    __syncthreads();
    if (threadIdx.x < 128) hin[threadIdx.x] = h[threadIdx.x];
    __syncthreads();
    #pragma unroll
    for (int off = 1; off < 128; off <<= 1) {   // Hillis-Steele inclusive scan
        int t = 0;
        if (threadIdx.x < 128 && (int)threadIdx.x >= off) t = h[threadIdx.x - off];
        __syncthreads();
        if (threadIdx.x < 128) h[threadIdx.x] += t;
        __syncthreads();
    }
    if (threadIdx.x < 128) {
        int excl = h[threadIdx.x] - hin[threadIdx.x];
        lcur[threadIdx.x] = excl;
        int node = b * 128 + threadIdx.x;
        if (node < N_NODES) rs[node] = s + excl;
    }
    if (b == NBUCK - 1 && threadIdx.x == 0) rs[N_NODES] = bbase[NBUCK];
    __syncthreads();
    for (int i = threadIdx.x; i < n; i += 256) {
        int v = lsrc[i];
        int r = atomicAdd(&lcur[v >> 17], 1);
        ssrc[s + r] = v & 0x1FFFF;   // scattered only within this bucket's 12 KB
    }
}

// ---- mean aggregation v5: one dst per 16-lane group, unroll 8 for MLP ----
// 8 independent 16B row loads in flight per group (~2x round-8 in-flight bytes)
// to cover LLC latency. BN+ReLU applied on the fly from a 512 B LDS table.
__global__ __launch_bounds__(256) void aggregate_kernel(const _Float16* __restrict__ Y,
                                                        const int* __restrict__ rs,
                                                        const int* __restrict__ ssrc,
                                                        const float* __restrict__ gstats,
                                                        const float* __restrict__ g,
                                                        const float* __restrict__ b,
                                                        _Float16* __restrict__ AGG) {
    __shared__ _Float16 sc16[128], sh16[128];
    if (threadIdx.x < 128) {
        int col = threadIdx.x;
        float m = gstats[col] * (1.f / (float)N_NODES);
        float v = gstats[128 + col] * (1.f / (float)N_NODES) - m * m;
        float s = g[col] * rsqrtf(v + BN_EPS);
        sc16[col] = (_Float16)s;
        sh16[col] = (_Float16)(b[col] - m * s);
    }
    __syncthreads();

    int wid = (blockIdx.x * 256 + threadIdx.x) >> 6;   // global wave id
    int lane = threadIdx.x & 63;
    int grp = lane >> 4, l16 = lane & 15;
    int dst = wid * 4 + grp;                           // exact: 25000 waves x 4
    int e0 = rs[dst], e1 = rs[dst + 1];
    int deg = e1 - e0;

    half8 scv = *(const half8*)(sc16 + l16 * 8);
    half8 shv = *(const half8*)(sh16 + l16 * 8);
    half8 acca = {0, 0, 0, 0, 0, 0, 0, 0};
    half8 accb = {0, 0, 0, 0, 0, 0, 0, 0};
    const _Float16* __restrict__ Yc = Y + l16 * 8;

    int e = e0;
    for (; e + 8 <= e1; e += 8) {
        int s0 = ssrc[e],     s1 = ssrc[e + 1], s2 = ssrc[e + 2], s3 = ssrc[e + 3];
        int s4 = ssrc[e + 4], s5 = ssrc[e + 5], s6 = ssrc[e + 6], s7 = ssrc[e + 7];
        half8 v0 = *(const half8*)(Yc + (long)s0 * HD);
        half8 v1 = *(const half8*)(Yc + (long)s1 * HD);
        half8 v2 = *(const half8*)(Yc + (long)s2 * HD);
        half8 v3 = *(const half8*)(Yc + (long)s3 * HD);
        half8 v4 = *(const half8*)(Yc + (long)s4 * HD);
        half8 v5 = *(const half8*)(Yc + (long)s5 * HD);
        half8 v6 = *(const half8*)(Yc + (long)s6 * HD);
        half8 v7 = *(const half8*)(Yc + (long)s7 * HD);
        acca += (bnrelu8(v0, scv, shv) + bnrelu8(v1, scv, shv)) +
                (bnrelu8(v2, scv, shv) + bnrelu8(v3, scv, shv));
        accb += (bnrelu8(v4, scv, shv) + bnrelu8(v5, scv, shv)) +
                (bnrelu8(v6, scv, shv) + bnrelu8(v7, scv, shv));
    }
    for (; e + 4 <= e1; e += 4) {
        int s0 = ssrc[e], s1 = ssrc[e + 1], s2 = ssrc[e + 2], s3 = ssrc[e + 3];
        half8 v0 = *(const half8*)(Yc + (long)s0 * HD);
        half8 v1 = *(const half8*)(Yc + (long)s1 * HD);
        half8 v2 = *(const half8*)(Yc + (long)s2 * HD);
        half8 v3 = *(const half8*)(Yc + (long)s3 * HD);
        acca += bnrelu8(v0, scv, shv) + bnrelu8(v1, scv, shv);
        accb += bnrelu8(v2, scv, shv) + bnrelu8(v3, scv, shv);
    }
    for (; e < e1; ++e) {
        half8 v0 = *(const half8*)(Yc + (long)ssrc[e] * HD);
        acca += bnrelu8(v0, scv, shv);
    }
    half8 acc = acca + accb;
    _Float16 inv = (_Float16)(1.f / (float)max(deg, 1));
    acc *= inv;
    *(half8*)(AGG + (long)dst * HD + l16 * 8) = acc;
}

// ---- MFMA GEMM: Y[r][c] = concat(A0, bnrelu(A1))[r][:] . Wt[c][:] + bias[c] ----
// B staged in LDS in fragment order (conflict-free ds_read_b128). BN_A1: the
// root-path fragments (k >= 128) get relu(sc*v+sh) applied from an LDS table.
// STATS: column sums/sq-sums -> one global atomicAdd per column into gstats_out.
template <int CT, int KS, bool HAS_A1, bool A_F32, bool OUT_F32, bool STATS, bool BN_A1>
__global__ __launch_bounds__(256, 2) void gemm_kernel(const void* __restrict__ A0v,
                                                      const _Float16* __restrict__ A1,
                                                      const _Float16* __restrict__ Wt,
                                                      const float* __restrict__ bias,
                                                      void* __restrict__ Yv,
                                                      int out_stride, int ncols,
                                                      float* __restrict__ gstats_out,
                                                      const float* __restrict__ bn_stats,
                                                      const float* __restrict__ bn_g,
                                                      const float* __restrict__ bn_b) {
    constexpr int K = KS * 32;
    constexpr int KSC = (KS > 4) ? 4 : KS;              // K-chunk = KSC*32 <= 128
    __shared__ _Float16 bsm[KSC * 32 * CT * 16];        // <= 32 KB
    __shared__ _Float16 a1sc[128], a1sh[128];
    int wave = threadIdx.x >> 6;
    int lane = threadIdx.x & 63;
    int quad = lane >> 4;
    int l16 = lane & 15;
    int row_base = (blockIdx.x * 4 + wave) * 32;
    bool active = row_base < N_NODES;

    if (BN_A1) {
        if (threadIdx.x < 128) {
            int col = threadIdx.x;
            float m = bn_stats[col] * (1.f / (float)N_NODES);
            float v = bn_stats[128 + col] * (1.f / (float)N_NODES) - m * m;
            float s = bn_g[col] * rsqrtf(v + BN_EPS);
            a1sc[col] = (_Float16)s;
            a1sh[col] = (_Float16)(bn_b[col] - m * s);
        }
        // covered by the staging __syncthreads below
    }

    floatx4 acc[2][CT];
    #pragma unroll
    for (int rt = 0; rt < 2; ++rt)
        #pragma unroll
        for (int c = 0; c < CT; ++c)
            acc[rt][c] = (floatx4){0.f, 0.f, 0.f, 0.f};

    for (int ch = 0; ch < KS; ch += KSC) {
        if (ch) __syncthreads();   // previous chunk fully consumed
        for (int i = threadIdx.x; i < KSC * CT * 64; i += 256) {
            int n = i % (CT * 16);
            int ko = i / (CT * 16);                      // octet index in chunk
            half8 v = *(const half8*)(Wt + n * K + (ch * 4 + ko) * 8);
            int slot = (((ko >> 2) * CT + (n >> 4)) * 4 + (ko & 3)) * 16 + (n & 15);
            *(half8*)(bsm + slot * 8) = v;
        }
        __syncthreads();
        if (active) {
            #pragma unroll
            for (int s2 = 0; s2 < KSC; ++s2) {
                int s = ch + s2;
                int kk = s * 32 + quad * 8;
                bool fromA1 = HAS_A1 && (kk >= 128);
                half8 afrag[2];
                #pragma unroll
                for (int rt = 0; rt < 2; ++rt) {
                    int r = row_base + rt * 16 + l16;
                    if (r > N_NODES - 1) r = N_NODES - 1;  // clamp read, store guarded below
                    if (A_F32) {
                        const float* p = (const float*)A0v + (long)r * 128 + kk;
                        floatx4 f0 = *(const floatx4*)p;
                        floatx4 f1 = *(const floatx4*)(p + 4);
                        #pragma unroll
                        for (int j = 0; j < 4; ++j) {
                            afrag[rt][j]     = (_Float16)f0[j];
                            afrag[rt][4 + j] = (_Float16)f1[j];
                        }
                    } else {
                        const _Float16* p;
                        if (fromA1) p = A1 + (long)r * 128 + (kk - 128);
                        else        p = (const _Float16*)A0v + (long)r * 128 + kk;
                        afrag[rt] = *(const half8*)p;
                        if (BN_A1 && fromA1) {
                            half8 s8 = *(const half8*)(a1sc + (kk - 128));
                            half8 h8 = *(const half8*)(a1sh + (kk - 128));
                            afrag[rt] = bnrelu8(afrag[rt], s8, h8);
                        }
                    }
                }
                #pragma unroll
                for (int c = 0; c < CT; ++c) {
                    half8 bfrag = *(const half8*)(bsm + ((s2 * CT + c) * 64 + lane) * 8);
                    #pragma unroll
                    for (int rt = 0; rt < 2; ++rt)
                        acc[rt][c] = __builtin_amdgcn_mfma_f32_16x16x32_f16(afrag[rt], bfrag, acc[rt][c], 0, 0, 0);
                }
            }
        }
    }

    float* lsum = (float*)bsm;      // overlay stats on B-buffer (done with it)
    float* lsq  = lsum + 128;
    if (STATS) {
        __syncthreads();
        if (threadIdx.x < 128) { lsum[threadIdx.x] = 0.f; lsq[threadIdx.x] = 0.f; }
        __syncthreads();
    } else {
        if (!active) return;
    }

    #pragma unroll
    for (int c = 0; c < CT; ++c) {
        int col = c * 16 + l16;
        float s_c = 0.f, q_c = 0.f;
        if (active && col < ncols) {
            float bv = bias[col];
            #pragma unroll
            for (int rt = 0; rt < 2; ++rt) {
                #pragma unroll
                for (int i = 0; i < 4; ++i) {
                    int r = row_base + rt * 16 + quad * 4 + i;
                    if (r < N_NODES) {
                        float v = acc[rt][c][i] + bv;
                        if (OUT_F32) ((float*)Yv)[(long)r * out_stride + col] = v;
                        else         ((_Float16*)Yv)[(long)r * out_stride + col] = (_Float16)v;
                        if (STATS) { s_c += v; q_c += v * v; }
                    }
                }
            }
        }
        if (STATS) {
            s_c += __shfl_xor(s_c, 16); s_c += __shfl_xor(s_c, 32);
            q_c += __shfl_xor(q_c, 16); q_c += __shfl_xor(q_c, 32);
            if (lane < 16 && active) {
                atomicAdd(&lsum[col], s_c);
                atomicAdd(&lsq[col], q_c);
            }
        }
    }

    if (STATS) {
        __syncthreads();
        if (threadIdx.x < 128) {
            atomicAdd(&gstats_out[threadIdx.x], lsum[threadIdx.x]);
            atomicAdd(&gstats_out[128 + threadIdx.x], lsq[threadIdx.x]);
        }
    }
}

extern "C" void kernel_launch(void* const* d_in, const int* in_sizes, int n_in,
                              void* d_out, int out_size, void* d_ws, size_t ws_size,
                              hipStream_t stream) {
    (void)in_sizes; (void)n_in; (void)out_size; (void)ws_size;
    const float* x       = (const float*)d_in[0];
    const float* W_in    = (const float*)d_in[1];
    const float* b_in    = (const float*)d_in[2];
    const float* g_in    = (const float*)d_in[3];
    const float* beta_in = (const float*)d_in[4];
    const float* Wl      = (const float*)d_in[5];
    const float* bl      = (const float*)d_in[6];
    const float* Wr      = (const float*)d_in[7];
    const float* g_bn    = (const float*)d_in[8];
    const float* b_bn    = (const float*)d_in[9];
    const float* W_out   = (const float*)d_in[10];
    const float* b_out   = (const float*)d_in[11];
    const int*   ei      = (const int*)d_in[12];
    const int* esrc = ei;
    const int* edst = ei + N_EDGES;
    float* out = (float*)d_out;

    char* w = (char*)d_ws;
    auto alloc = [&](size_t bytes) -> char* {
        char* p = w; w += (bytes + 255) & ~(size_t)255; return p;
    };
    int* rs           = (int*)alloc((N_NODES + 1) * sizeof(int));
    int* bcnt         = (int*)alloc((NBUCK + 1) * sizeof(int));
    int* bbase        = (int*)alloc((NBUCK + 1) * sizeof(int));
    int* bcur         = (int*)alloc(NBUCK * sizeof(int));
    int* ssrc         = (int*)alloc(N_EDGES * sizeof(int));
    _Float16* Wt_in   = (_Float16*)alloc(128 * 128 * 2);
    _Float16* Wt_cat  = (_Float16*)alloc(4 * 128 * 256 * 2);
    _Float16* Wt_out  = (_Float16*)alloc(48 * 128 * 2);
    _Float16* ybufA   = (_Float16*)alloc((size_t)N_NODES * HD * 2);
    _Float16* ybufB   = (_Float16*)alloc((size_t)N_NODES * HD * 2);
    _Float16* agg     = (_Float16*)alloc((size_t)N_NODES * HD * 2);
    float* gstats     = (float*)alloc(4 * 256 * 4);   // [layer][sum128|sq128]
    int* bedges       = (int*)agg;   // alias: dead before first aggregate

    hipMemsetAsync(bcnt, 0, (NBUCK + 1) * sizeof(int), stream);
    hipMemsetAsync(gstats, 0, 4 * 256 * 4, stream);
    prep_kernel<<<256, 256, 0, stream>>>(W_in, Wl, Wr, W_out, Wt_in, Wt_cat, Wt_out);
    bucket_hist_kernel<<<256, 256, 0, stream>>>(edst, bcnt);
    bucket_scan_kernel<<<1, 64, 0, stream>>>(bcnt, bbase, bcur);
    bucket_scatter_kernel<<<(N_EDGES + 512 * SCAT_T - 1) / (512 * SCAT_T), 512, 0, stream>>>(
        esrc, edst, bcur, bedges);
    bucket_sort_kernel<<<NBUCK, 256, 0, stream>>>(bedges, bbase, rs, ssrc);

    // input layer: y0 = x @ W_in + b_in (stats -> gstats[0]); BN deferred to consumers
    gemm_kernel<8, 4, false, true, false, true, false><<<GB, 256, 0, stream>>>(
        x, nullptr, Wt_in, b_in, ybufA, HD, HD, gstats, nullptr, nullptr, nullptr);

    _Float16* cur = ybufA;
    _Float16* nxt = ybufB;
    for (int i = 0; i < NLAYERS; ++i) {
        const float* gs   = gstats + i * 256;
        const float* bn_g = (i == 0) ? g_in    : g_bn + (i - 1) * 128;
        const float* bn_b = (i == 0) ? beta_in : b_bn + (i - 1) * 128;
        aggregate_kernel<<<N_NODES / 16, 256, 0, stream>>>(cur, rs, ssrc, gs, bn_g, bn_b, agg);
        if (i < NLAYERS - 1) {
            gemm_kernel<8, 8, true, false, false, true, true><<<GB, 256, 0, stream>>>(
                agg, cur, Wt_cat + i * 128 * 256, bl + i * 128, nxt, HD, HD,
                gstats + (i + 1) * 256, gs, bn_g, bn_b);
        } else {
            gemm_kernel<8, 8, true, false, false, false, true><<<GB, 256, 0, stream>>>(
                agg, cur, Wt_cat + i * 128 * 256, bl + i * 128, nxt, HD, HD,
                nullptr, gs, bn_g, bn_b);
        }
        _Float16* t = cur; cur = nxt; nxt = t;
    }

    // output layer: out = y4 @ W_out + b_out  (y4 == cur, no BN on last layer)
    gemm_kernel<3, 4, false, false, true, false, false><<<GB, 256, 0, stream>>>(
        cur, nullptr, Wt_out, b_out, out, COUT, COUT, nullptr, nullptr, nullptr, nullptr);
}